// Round 3
// baseline (249.636 us; speedup 1.0000x reference)
//
#include <hip/hip_runtime.h>
#include <hip/hip_bf16.h>
#include <cstdint>
#include <cstddef>

#define BATCH 8
#define SEQ   4096
#define CDIM  384
#define HDIM  64

typedef __attribute__((ext_vector_type(8))) __bf16 bf16x8;
typedef __attribute__((ext_vector_type(4))) float  f32x4;
typedef __attribute__((ext_vector_type(4))) short  short4v;

#if __has_builtin(__builtin_amdgcn_mfma_f32_16x16x16bf16_1k)
#define HAVE_MFMA161616 1
#else
#define HAVE_MFMA161616 0
#endif

static __device__ __forceinline__ short f2bf(float f) {
  union { float f; uint32_t u; } v; v.f = f;
  uint32_t r = v.u + 0x7fffu + ((v.u >> 16) & 1u);
  return (short)(r >> 16);
}

static __device__ __forceinline__ f32x4 mfma16(bf16x8 a, bf16x8 b, f32x4 c) {
  return __builtin_amdgcn_mfma_f32_16x16x32_bf16(a, b, c, 0, 0, 0);
}

static __device__ __forceinline__ f32x4 zero4() {
  f32x4 z = {0.f, 0.f, 0.f, 0.f};
  return z;
}

// ---------------------------------------------------------------------------
// Pack Wq|Wk|Wv into Wt [192][384] bf16 (transposed, K contiguous).  Wq is
// prescaled by 0.125*log2(e): softmax runs in base 2 with no extra multiply.
// ---------------------------------------------------------------------------
__global__ __launch_bounds__(256) void wpack_kernel(
    const float* __restrict__ Wq, const float* __restrict__ Wk,
    const float* __restrict__ Wv, short* __restrict__ Wt) {
  int idx = blockIdx.x * 256 + threadIdx.x;
  if (idx >= 192 * CDIM) return;
  int n = idx / CDIM;
  int c = idx - n * CDIM;
  int m = n >> 6, h = n & 63;
  const float* W = (m == 0) ? Wq : (m == 1) ? Wk : Wv;
  float s = (m == 0) ? 0.18033688011112042f : 1.0f;  // 0.125 * log2(e)
  Wt[idx] = f2bf(W[c * HDIM + h] * s);
}

// ---------------------------------------------------------------------------
// QKV projection: x [32768][384] f32 -> q,k [b][t][64] bf16, v transposed
// vT [b][64][t] bf16.
// ---------------------------------------------------------------------------
#define XPAD 392

__global__ __launch_bounds__(256) void qkv_kernel(
    const float* __restrict__ x, const short* __restrict__ Wt,
    short* __restrict__ qb, short* __restrict__ kb, short* __restrict__ vT) {
  __shared__ short xs[64 * XPAD];
  const int tid = threadIdx.x;
  const int tokbase = blockIdx.x * 64;

  const float4* xg = (const float4*)(x + (size_t)tokbase * CDIM);
  for (int it = tid; it < 64 * (CDIM / 4); it += 256) {
    int r  = it / (CDIM / 4);
    int c4 = it - r * (CDIM / 4);
    float4 v = xg[it];
    short4v s;
    s[0] = f2bf(v.x); s[1] = f2bf(v.y); s[2] = f2bf(v.z); s[3] = f2bf(v.w);
    *(short4v*)&xs[r * XPAD + c4 * 4] = s;
  }
  __syncthreads();

  const int wave = tid >> 6;
  const int lane = tid & 63;
  const int l16  = lane & 15;
  const int lq   = lane >> 4;

  f32x4 acc[4][3];
  #pragma unroll
  for (int ai = 0; ai < 4; ++ai)
    #pragma unroll
    for (int j = 0; j < 3; ++j) acc[ai][j] = zero4();

  #pragma unroll 2
  for (int kk = 0; kk < CDIM / 32; ++kk) {
    const int k0 = kk * 32;
    bf16x8 a[4];
    #pragma unroll
    for (int ai = 0; ai < 4; ++ai)
      a[ai] = *(const bf16x8*)&xs[(ai * 16 + l16) * XPAD + k0 + lq * 8];
    bf16x8 bb[3];
    #pragma unroll
    for (int j = 0; j < 3; ++j) {
      const int nt = wave * 3 + j;
      bb[j] = *(const bf16x8*)&Wt[(size_t)(nt * 16 + l16) * CDIM + k0 + lq * 8];
    }
    #pragma unroll
    for (int ai = 0; ai < 4; ++ai)
      #pragma unroll
      for (int j = 0; j < 3; ++j)
        acc[ai][j] = mfma16(a[ai], bb[j], acc[ai][j]);
  }

  const int b     = tokbase >> 12;
  const int tloc0 = tokbase & (SEQ - 1);
  #pragma unroll
  for (int j = 0; j < 3; ++j) {
    const int col = (wave * 3 + j) * 16 + l16;
    const int mat = col >> 6;
    const int h   = col & 63;
    #pragma unroll
    for (int ai = 0; ai < 4; ++ai) {
      const int row0 = ai * 16 + lq * 4;
      if (mat < 2) {
        short* dst = mat ? kb : qb;
        #pragma unroll
        for (int r = 0; r < 4; ++r)
          dst[(size_t)(tokbase + row0 + r) * HDIM + h] = f2bf(acc[ai][j][r]);
      } else {
        short4v s;
        #pragma unroll
        for (int r = 0; r < 4; ++r) s[r] = f2bf(acc[ai][j][r]);
        *(short4v*)&vT[(size_t)(b * HDIM + h) * SEQ + (tloc0 + row0)] = s;
      }
    }
  }
}

// ---------------------------------------------------------------------------
// Causal flash attention.  Block (1024 total) = batch b (bid&7, XCD-pinned)
// + pair index pidx (bid>>3): q-tiles qtA=pidx, qtB=255-pidx (16 rows each).
// Every wave w processes BOTH tiles, s-tiles st ≡ w (mod 4) -> exactly
// 16-17 KV iters per wave, for all 4096 waves.  Per-tile partials (m,l,O)
// merged across the 4 waves through LDS at block end.
// ---------------------------------------------------------------------------
#define OP 68  // 64 + 4 pad (floats)

static __device__ __forceinline__ void process_tile(
    const short* __restrict__ qb, const short* __restrict__ kbase,
    const short* __restrict__ vrow0, size_t bT, int qt, int w,
    int l16, int lq, float& m, float& l, f32x4 (&oacc)[4]) {
  const int nst = (qt >> 2) + 1;
  const int cnt = (nst > w) ? ((nst - w + 3) >> 2) : 0;
  if (cnt == 0) return;
  const int q0 = qt << 4;

  bf16x8 qf0, qf1;
  {
    const short* qrow = qb + (bT + q0 + l16) * HDIM + lq * 8;
    qf0 = *(const bf16x8*)qrow;
    qf1 = *(const bf16x8*)(qrow + 32);
  }

  int st = w;
  bf16x8 kc[4][2];
  #pragma unroll
  for (int n = 0; n < 4; ++n) {
    const short* kr = kbase + (size_t)(st * 64 + n * 16 + l16) * HDIM;
    kc[n][0] = *(const bf16x8*)kr;
    kc[n][1] = *(const bf16x8*)(kr + 32);
  }

  for (int k = 0; k < cnt; ++k, st += 4) {
    const int s0  = st * 64;
    const int s0n = (k + 1 < cnt) ? s0 + 256 : s0;

    // V loads for this iter (consumed at the end)
#if HAVE_MFMA161616
    short4v vf[4][4];
    #pragma unroll
    for (int j = 0; j < 4; ++j)
      #pragma unroll
      for (int n = 0; n < 4; ++n)
        vf[j][n] = *(const short4v*)(vrow0 + (size_t)(j * 16) * SEQ +
                                     s0 + n * 16 + lq * 4);
#else
    bf16x8 vf[4][2];
    #pragma unroll
    for (int j = 0; j < 4; ++j)
      #pragma unroll
      for (int sh = 0; sh < 2; ++sh)
        vf[j][sh] = *(const bf16x8*)(vrow0 + (size_t)(j * 16) * SEQ +
                                     s0 + sh * 32 + lq * 8);
#endif
    // prefetch K(next st)
    bf16x8 kn[4][2];
    #pragma unroll
    for (int n = 0; n < 4; ++n) {
      const short* kr = kbase + (size_t)(s0n + n * 16 + l16) * HDIM;
      kn[n][0] = *(const bf16x8*)kr;
      kn[n][1] = *(const bf16x8*)(kr + 32);
    }

    // S^T = mfma(K, Q): sacc[n][r] = S[q=l16][s=s0+n*16+lq*4+r]
    f32x4 sacc[4];
    #pragma unroll
    for (int n = 0; n < 4; ++n) {
      sacc[n] = mfma16(kc[n][0], qf0, zero4());
      sacc[n] = mfma16(kc[n][1], qf1, sacc[n]);
    }

    // causal mask: only the diagonal tile (wave-uniform branch)
    if (s0 + 63 > q0) {
      const int qg = q0 + l16;
      #pragma unroll
      for (int n = 0; n < 4; ++n) {
        const int sg = s0 + n * 16 + lq * 4;
        #pragma unroll
        for (int r = 0; r < 4; ++r)
          if (sg + r > qg) sacc[n][r] = -1e30f;
      }
    }

    // per-q max: register tree + 2 shfl_xor across lq
    float pm;
    {
      float t0 = fmaxf(fmaxf(sacc[0][0], sacc[0][1]), fmaxf(sacc[0][2], sacc[0][3]));
      float t1 = fmaxf(fmaxf(sacc[1][0], sacc[1][1]), fmaxf(sacc[1][2], sacc[1][3]));
      float t2 = fmaxf(fmaxf(sacc[2][0], sacc[2][1]), fmaxf(sacc[2][2], sacc[2][3]));
      float t3 = fmaxf(fmaxf(sacc[3][0], sacc[3][1]), fmaxf(sacc[3][2], sacc[3][3]));
      pm = fmaxf(fmaxf(t0, t1), fmaxf(t2, t3));
    }
    pm = fmaxf(pm, __shfl_xor(pm, 16, 64));
    pm = fmaxf(pm, __shfl_xor(pm, 32, 64));

    // defer-max rescale (T13)
    if (!__all(pm <= m)) {
      const float mn = fmaxf(m, pm);
      const float sc = exp2f(m - mn);
      m = mn; l *= sc;
      #pragma unroll
      for (int j = 0; j < 4; ++j)
        #pragma unroll
        for (int r = 0; r < 4; ++r) oacc[j][r] *= sc;
    }

    // P = 2^(S - m), row sum
    float p[4][4];
    #pragma unroll
    for (int n = 0; n < 4; ++n)
      #pragma unroll
      for (int r = 0; r < 4; ++r) p[n][r] = exp2f(sacc[n][r] - m);
    float rs = ((p[0][0] + p[0][1]) + (p[0][2] + p[0][3]))
             + ((p[1][0] + p[1][1]) + (p[1][2] + p[1][3]))
             + ((p[2][0] + p[2][1]) + (p[2][2] + p[2][3]))
             + ((p[3][0] + p[3][1]) + (p[3][2] + p[3][3]));
    rs += __shfl_xor(rs, 16, 64);
    rs += __shfl_xor(rs, 32, 64);
    l += rs;

    uint32_t w32[4][2];
    #pragma unroll
    for (int n = 0; n < 4; ++n)
      #pragma unroll
      for (int c = 0; c < 2; ++c)
        asm("v_cvt_pk_bf16_f32 %0, %1, %2"
            : "=v"(w32[n][c]) : "v"(p[n][2 * c]), "v"(p[n][2 * c + 1]));

    // O^T += V^T P^T
#if HAVE_MFMA161616
    #pragma unroll
    for (int j = 0; j < 4; ++j) {
      #pragma unroll
      for (int n = 0; n < 4; ++n) {
        union { uint32_t u[2]; short4v s; } pb;
        pb.u[0] = w32[n][0]; pb.u[1] = w32[n][1];
        oacc[j] = __builtin_amdgcn_mfma_f32_16x16x16bf16_1k(vf[j][n], pb.s,
                                                            oacc[j], 0, 0, 0);
      }
    }
#else
    union { uint32_t u[4]; bf16x8 v; } pf0, pf1;
    #pragma unroll
    for (int aa = 0; aa < 4; ++aa) {
      const int src = l16 + ((((lq << 1) + (aa >> 1)) & 3) << 4);
      uint32_t lo0 = (uint32_t)__shfl((int)w32[0][aa & 1], src, 64);
      uint32_t hi0 = (uint32_t)__shfl((int)w32[1][aa & 1], src, 64);
      uint32_t lo1 = (uint32_t)__shfl((int)w32[2][aa & 1], src, 64);
      uint32_t hi1 = (uint32_t)__shfl((int)w32[3][aa & 1], src, 64);
      pf0.u[aa] = (lq & 2) ? hi0 : lo0;
      pf1.u[aa] = (lq & 2) ? hi1 : lo1;
    }
    #pragma unroll
    for (int j = 0; j < 4; ++j) {
      oacc[j] = mfma16(vf[j][0], pf0.v, oacc[j]);
      oacc[j] = mfma16(vf[j][1], pf1.v, oacc[j]);
    }
#endif

    #pragma unroll
    for (int n = 0; n < 4; ++n) {
      kc[n][0] = kn[n][0];
      kc[n][1] = kn[n][1];
    }
  }
}

__global__ __launch_bounds__(256, 4) void attn_kernel(
    const short* __restrict__ qb, const short* __restrict__ kb,
    const short* __restrict__ vT, float* __restrict__ out) {
  __shared__ float o_lds[2][4][16][OP];
  __shared__ float ml_lds[2][4][2][16];

  const int tid  = threadIdx.x;
  const int wave = tid >> 6;
  const int lane = tid & 63;
  const int l16  = lane & 15;
  const int lq   = lane >> 4;
  const int bid  = blockIdx.x;
  const int b    = bid & 7;           // batch -> XCD pin
  const int pidx = bid >> 3;          // 0..127
  const int qtA  = pidx;
  const int qtB  = 255 - pidx;

  const size_t bT = (size_t)b * SEQ;
  const short* kbase = kb + bT * HDIM + lq * 8;
  const short* vrow0 = vT + ((size_t)b * HDIM + l16) * SEQ;

  float mA = -1e30f, lA = 0.f, mB = -1e30f, lB = 0.f;
  f32x4 oA[4], oB[4];
  #pragma unroll
  for (int j = 0; j < 4; ++j) { oA[j] = zero4(); oB[j] = zero4(); }

  process_tile(qb, kbase, vrow0, bT, qtA, wave, l16, lq, mA, lA, oA);
  process_tile(qb, kbase, vrow0, bT, qtB, wave, l16, lq, mB, lB, oB);

  // ---- write partials ----
  #pragma unroll
  for (int j4 = 0; j4 < 4; ++j4) {
    float4 a, c;
    a.x = oA[j4][0]; a.y = oA[j4][1]; a.z = oA[j4][2]; a.w = oA[j4][3];
    c.x = oB[j4][0]; c.y = oB[j4][1]; c.z = oB[j4][2]; c.w = oB[j4][3];
    *(float4*)&o_lds[0][wave][l16][j4 * 16 + lq * 4] = a;
    *(float4*)&o_lds[1][wave][l16][j4 * 16 + lq * 4] = c;
  }
  if (lq == 0) {
    ml_lds[0][wave][0][l16] = mA; ml_lds[0][wave][1][l16] = lA;
    ml_lds[1][wave][0][l16] = mB; ml_lds[1][wave][1][l16] = lB;
  }
  __syncthreads();

  // ---- merge: wave w -> tile w>>1, rows (w&1)*8 + lane>>3 ----
  const int t    = wave >> 1;
  const int row  = ((wave & 1) << 3) + (lane >> 3);
  const int col0 = (lane & 7) << 3;
  const int qt_t = t ? qtB : qtA;

  float m0 = ml_lds[t][0][0][row], m1 = ml_lds[t][1][0][row];
  float m2 = ml_lds[t][2][0][row], m3 = ml_lds[t][3][0][row];
  float mm = fmaxf(fmaxf(m0, m1), fmaxf(m2, m3));
  float w0 = exp2f(m0 - mm), w1 = exp2f(m1 - mm);
  float w2 = exp2f(m2 - mm), w3 = exp2f(m3 - mm);
  float ls = w0 * ml_lds[t][0][1][row] + w1 * ml_lds[t][1][1][row]
           + w2 * ml_lds[t][2][1][row] + w3 * ml_lds[t][3][1][row];

  float acc[8];
  #pragma unroll
  for (int c = 0; c < 8; ++c) acc[c] = 0.f;
  const float wgt[4] = {w0, w1, w2, w3};
  #pragma unroll
  for (int p = 0; p < 4; ++p) {
    float4 a = *(float4*)&o_lds[t][p][row][col0];
    float4 c = *(float4*)&o_lds[t][p][row][col0 + 4];
    acc[0] += wgt[p] * a.x; acc[1] += wgt[p] * a.y;
    acc[2] += wgt[p] * a.z; acc[3] += wgt[p] * a.w;
    acc[4] += wgt[p] * c.x; acc[5] += wgt[p] * c.y;
    acc[6] += wgt[p] * c.z; acc[7] += wgt[p] * c.w;
  }
  const float inv = 1.0f / ls;
  float4 r0, r1;
  r0.x = acc[0] * inv; r0.y = acc[1] * inv; r0.z = acc[2] * inv; r0.w = acc[3] * inv;
  r1.x = acc[4] * inv; r1.y = acc[5] * inv; r1.z = acc[6] * inv; r1.w = acc[7] * inv;
  float* orow = out + (bT + (size_t)qt_t * 16 + row) * HDIM + col0;
  *(float4*)orow       = r0;
  *(float4*)(orow + 4) = r1;
}

// ---------------------------------------------------------------------------
extern "C" void kernel_launch(void* const* d_in, const int* in_sizes, int n_in,
                              void* d_out, int out_size, void* d_ws, size_t ws_size,
                              hipStream_t stream) {
  (void)in_sizes; (void)n_in; (void)out_size; (void)ws_size;
  const float* x  = (const float*)d_in[0];
  const float* Wq = (const float*)d_in[1];
  const float* Wk = (const float*)d_in[2];
  const float* Wv = (const float*)d_in[3];

  const size_t qkvb = (size_t)BATCH * SEQ * HDIM * sizeof(short);  // 4 MB each
  char* ws = (char*)d_ws;
  short* qb = (short*)(ws);
  short* kb = (short*)(ws + qkvb);
  short* vT = (short*)(ws + 2 * qkvb);
  short* Wt = (short*)(ws + 3 * qkvb);

  wpack_kernel<<<dim3((192 * CDIM + 255) / 256), dim3(256), 0, stream>>>(Wq, Wk, Wv, Wt);
  qkv_kernel<<<dim3(BATCH * SEQ / 64), dim3(256), 0, stream>>>(x, Wt, qb, kb, vT);
  attn_kernel<<<dim3(1024), dim3(256), 0, stream>>>(qb, kb, vT, (float*)d_out);
}

// Round 4
// 211.745 us; speedup vs baseline: 1.1789x; 1.1789x over previous
//
#include <hip/hip_runtime.h>
#include <hip/hip_bf16.h>
#include <cstdint>
#include <cstddef>

#define BATCH 8
#define SEQ   4096
#define CDIM  384
#define HDIM  64

typedef __attribute__((ext_vector_type(8))) __bf16 bf16x8;
typedef __attribute__((ext_vector_type(4))) float  f32x4;
typedef __attribute__((ext_vector_type(4))) short  short4v;

#if __has_builtin(__builtin_amdgcn_mfma_f32_16x16x16bf16_1k)
#define HAVE_MFMA161616 1
#else
#define HAVE_MFMA161616 0
#endif

static __device__ __forceinline__ short f2bf(float f) {
  union { float f; uint32_t u; } v; v.f = f;
  uint32_t r = v.u + 0x7fffu + ((v.u >> 16) & 1u);
  return (short)(r >> 16);
}

static __device__ __forceinline__ f32x4 mfma16(bf16x8 a, bf16x8 b, f32x4 c) {
  return __builtin_amdgcn_mfma_f32_16x16x32_bf16(a, b, c, 0, 0, 0);
}

static __device__ __forceinline__ f32x4 zero4() {
  f32x4 z = {0.f, 0.f, 0.f, 0.f};
  return z;
}

// ---------------------------------------------------------------------------
// Pack Wq|Wk|Wv into Wt [192][384] bf16 (transposed, K contiguous).  Wq is
// prescaled by 0.125*log2(e): softmax runs in base 2 with no extra multiply.
// ---------------------------------------------------------------------------
__global__ __launch_bounds__(256) void wpack_kernel(
    const float* __restrict__ Wq, const float* __restrict__ Wk,
    const float* __restrict__ Wv, short* __restrict__ Wt) {
  int idx = blockIdx.x * 256 + threadIdx.x;
  if (idx >= 192 * CDIM) return;
  int n = idx / CDIM;
  int c = idx - n * CDIM;
  int m = n >> 6, h = n & 63;
  const float* W = (m == 0) ? Wq : (m == 1) ? Wk : Wv;
  float s = (m == 0) ? 0.18033688011112042f : 1.0f;  // 0.125 * log2(e)
  Wt[idx] = f2bf(W[c * HDIM + h] * s);
}

// ---------------------------------------------------------------------------
// QKV projection: x [32768][384] f32 -> q,k [b][t][64] bf16, v transposed
// vT [b][64][t] bf16.
// ---------------------------------------------------------------------------
#define XPAD 392

__global__ __launch_bounds__(256) void qkv_kernel(
    const float* __restrict__ x, const short* __restrict__ Wt,
    short* __restrict__ qb, short* __restrict__ kb, short* __restrict__ vT) {
  __shared__ short xs[64 * XPAD];
  const int tid = threadIdx.x;
  const int tokbase = blockIdx.x * 64;

  const float4* xg = (const float4*)(x + (size_t)tokbase * CDIM);
  for (int it = tid; it < 64 * (CDIM / 4); it += 256) {
    int r  = it / (CDIM / 4);
    int c4 = it - r * (CDIM / 4);
    float4 v = xg[it];
    short4v s;
    s[0] = f2bf(v.x); s[1] = f2bf(v.y); s[2] = f2bf(v.z); s[3] = f2bf(v.w);
    *(short4v*)&xs[r * XPAD + c4 * 4] = s;
  }
  __syncthreads();

  const int wave = tid >> 6;
  const int lane = tid & 63;
  const int l16  = lane & 15;
  const int lq   = lane >> 4;

  f32x4 acc[4][3];
  #pragma unroll
  for (int ai = 0; ai < 4; ++ai)
    #pragma unroll
    for (int j = 0; j < 3; ++j) acc[ai][j] = zero4();

  #pragma unroll 2
  for (int kk = 0; kk < CDIM / 32; ++kk) {
    const int k0 = kk * 32;
    bf16x8 a[4];
    #pragma unroll
    for (int ai = 0; ai < 4; ++ai)
      a[ai] = *(const bf16x8*)&xs[(ai * 16 + l16) * XPAD + k0 + lq * 8];
    bf16x8 bb[3];
    #pragma unroll
    for (int j = 0; j < 3; ++j) {
      const int nt = wave * 3 + j;
      bb[j] = *(const bf16x8*)&Wt[(size_t)(nt * 16 + l16) * CDIM + k0 + lq * 8];
    }
    #pragma unroll
    for (int ai = 0; ai < 4; ++ai)
      #pragma unroll
      for (int j = 0; j < 3; ++j)
        acc[ai][j] = mfma16(a[ai], bb[j], acc[ai][j]);
  }

  const int b     = tokbase >> 12;
  const int tloc0 = tokbase & (SEQ - 1);
  #pragma unroll
  for (int j = 0; j < 3; ++j) {
    const int col = (wave * 3 + j) * 16 + l16;
    const int mat = col >> 6;
    const int h   = col & 63;
    #pragma unroll
    for (int ai = 0; ai < 4; ++ai) {
      const int row0 = ai * 16 + lq * 4;
      if (mat < 2) {
        short* dst = mat ? kb : qb;
        #pragma unroll
        for (int r = 0; r < 4; ++r)
          dst[(size_t)(tokbase + row0 + r) * HDIM + h] = f2bf(acc[ai][j][r]);
      } else {
        short4v s;
        #pragma unroll
        for (int r = 0; r < 4; ++r) s[r] = f2bf(acc[ai][j][r]);
        *(short4v*)&vT[(size_t)(b * HDIM + h) * SEQ + (tloc0 + row0)] = s;
      }
    }
  }
}

// ---------------------------------------------------------------------------
// Causal flash attention.  Block (1024 total) = batch b (bid&7, XCD-pinned)
// + pair index pidx (bid>>3): q-tiles qtA=pidx, qtB=255-pidx (16 rows each).
// Every wave w processes BOTH tiles, s-tiles st ≡ w (mod 4) -> exactly
// 16-17 KV iters per wave, uniformly across all 4096 waves.  Per-tile
// partials (m,l,O) go to LDS right after each tile (keeps register peak to
// one tile's working set); merged across the 4 waves at block end.
// ---------------------------------------------------------------------------
#define OP 68  // 64 + 4 pad (floats)

static __device__ __forceinline__ void process_tile(
    const short* __restrict__ qb, const short* __restrict__ kbase,
    const short* __restrict__ vrow0, size_t bT, int qt, int w,
    int l16, int lq, float& m, float& l, f32x4 (&oacc)[4]) {
  const int nst = (qt >> 2) + 1;
  const int cnt = (nst > w) ? ((nst - w + 3) >> 2) : 0;
  if (cnt == 0) return;
  const int q0 = qt << 4;

  bf16x8 qf0, qf1;
  {
    const short* qrow = qb + (bT + q0 + l16) * HDIM + lq * 8;
    qf0 = *(const bf16x8*)qrow;
    qf1 = *(const bf16x8*)(qrow + 32);
  }

  int st = w;
  bf16x8 kc[4][2];
  #pragma unroll
  for (int n = 0; n < 4; ++n) {
    const short* kr = kbase + (size_t)(st * 64 + n * 16 + l16) * HDIM;
    kc[n][0] = *(const bf16x8*)kr;
    kc[n][1] = *(const bf16x8*)(kr + 32);
  }

  for (int k = 0; k < cnt; ++k, st += 4) {
    const int s0  = st * 64;
    const int s0n = (k + 1 < cnt) ? s0 + 256 : s0;

    // V loads for this iter (consumed at the end)
#if HAVE_MFMA161616
    short4v vf[4][4];
    #pragma unroll
    for (int j = 0; j < 4; ++j)
      #pragma unroll
      for (int n = 0; n < 4; ++n)
        vf[j][n] = *(const short4v*)(vrow0 + (size_t)(j * 16) * SEQ +
                                     s0 + n * 16 + lq * 4);
#else
    bf16x8 vf[4][2];
    #pragma unroll
    for (int j = 0; j < 4; ++j)
      #pragma unroll
      for (int sh = 0; sh < 2; ++sh)
        vf[j][sh] = *(const bf16x8*)(vrow0 + (size_t)(j * 16) * SEQ +
                                     s0 + sh * 32 + lq * 8);
#endif
    // prefetch K(next st)
    bf16x8 kn[4][2];
    #pragma unroll
    for (int n = 0; n < 4; ++n) {
      const short* kr = kbase + (size_t)(s0n + n * 16 + l16) * HDIM;
      kn[n][0] = *(const bf16x8*)kr;
      kn[n][1] = *(const bf16x8*)(kr + 32);
    }

    // S^T = mfma(K, Q): sacc[n][r] = S[q=l16][s=s0+n*16+lq*4+r]
    f32x4 sacc[4];
    #pragma unroll
    for (int n = 0; n < 4; ++n) {
      sacc[n] = mfma16(kc[n][0], qf0, zero4());
      sacc[n] = mfma16(kc[n][1], qf1, sacc[n]);
    }

    // causal mask: only the diagonal tile (wave-uniform branch)
    if (s0 + 63 > q0) {
      const int qg = q0 + l16;
      #pragma unroll
      for (int n = 0; n < 4; ++n) {
        const int sg = s0 + n * 16 + lq * 4;
        #pragma unroll
        for (int r = 0; r < 4; ++r)
          if (sg + r > qg) sacc[n][r] = -1e30f;
      }
    }

    // per-q max: register tree + 2 shfl_xor across lq
    float pm;
    {
      float t0 = fmaxf(fmaxf(sacc[0][0], sacc[0][1]), fmaxf(sacc[0][2], sacc[0][3]));
      float t1 = fmaxf(fmaxf(sacc[1][0], sacc[1][1]), fmaxf(sacc[1][2], sacc[1][3]));
      float t2 = fmaxf(fmaxf(sacc[2][0], sacc[2][1]), fmaxf(sacc[2][2], sacc[2][3]));
      float t3 = fmaxf(fmaxf(sacc[3][0], sacc[3][1]), fmaxf(sacc[3][2], sacc[3][3]));
      pm = fmaxf(fmaxf(t0, t1), fmaxf(t2, t3));
    }
    pm = fmaxf(pm, __shfl_xor(pm, 16, 64));
    pm = fmaxf(pm, __shfl_xor(pm, 32, 64));

    // defer-max rescale (T13)
    if (!__all(pm <= m)) {
      const float mn = fmaxf(m, pm);
      const float sc = exp2f(m - mn);
      m = mn; l *= sc;
      #pragma unroll
      for (int j = 0; j < 4; ++j)
        #pragma unroll
        for (int r = 0; r < 4; ++r) oacc[j][r] *= sc;
    }

    // P = 2^(S - m), row sum
    float p[4][4];
    #pragma unroll
    for (int n = 0; n < 4; ++n)
      #pragma unroll
      for (int r = 0; r < 4; ++r) p[n][r] = exp2f(sacc[n][r] - m);
    float rs = ((p[0][0] + p[0][1]) + (p[0][2] + p[0][3]))
             + ((p[1][0] + p[1][1]) + (p[1][2] + p[1][3]))
             + ((p[2][0] + p[2][1]) + (p[2][2] + p[2][3]))
             + ((p[3][0] + p[3][1]) + (p[3][2] + p[3][3]));
    rs += __shfl_xor(rs, 16, 64);
    rs += __shfl_xor(rs, 32, 64);
    l += rs;

    uint32_t w32[4][2];
    #pragma unroll
    for (int n = 0; n < 4; ++n)
      #pragma unroll
      for (int c = 0; c < 2; ++c)
        asm("v_cvt_pk_bf16_f32 %0, %1, %2"
            : "=v"(w32[n][c]) : "v"(p[n][2 * c]), "v"(p[n][2 * c + 1]));

    // O^T += V^T P^T
#if HAVE_MFMA161616
    #pragma unroll
    for (int j = 0; j < 4; ++j) {
      #pragma unroll
      for (int n = 0; n < 4; ++n) {
        union { uint32_t u[2]; short4v s; } pb;
        pb.u[0] = w32[n][0]; pb.u[1] = w32[n][1];
        oacc[j] = __builtin_amdgcn_mfma_f32_16x16x16bf16_1k(vf[j][n], pb.s,
                                                            oacc[j], 0, 0, 0);
      }
    }
#else
    union { uint32_t u[4]; bf16x8 v; } pf0, pf1;
    #pragma unroll
    for (int aa = 0; aa < 4; ++aa) {
      const int src = l16 + ((((lq << 1) + (aa >> 1)) & 3) << 4);
      uint32_t lo0 = (uint32_t)__shfl((int)w32[0][aa & 1], src, 64);
      uint32_t hi0 = (uint32_t)__shfl((int)w32[1][aa & 1], src, 64);
      uint32_t lo1 = (uint32_t)__shfl((int)w32[2][aa & 1], src, 64);
      uint32_t hi1 = (uint32_t)__shfl((int)w32[3][aa & 1], src, 64);
      pf0.u[aa] = (lq & 2) ? hi0 : lo0;
      pf1.u[aa] = (lq & 2) ? hi1 : lo1;
    }
    #pragma unroll
    for (int j = 0; j < 4; ++j) {
      oacc[j] = mfma16(vf[j][0], pf0.v, oacc[j]);
      oacc[j] = mfma16(vf[j][1], pf1.v, oacc[j]);
    }
#endif

    #pragma unroll
    for (int n = 0; n < 4; ++n) {
      kc[n][0] = kn[n][0];
      kc[n][1] = kn[n][1];
    }
  }
}

__global__ __launch_bounds__(256, 2) void attn_kernel(
    const short* __restrict__ qb, const short* __restrict__ kb,
    const short* __restrict__ vT, float* __restrict__ out) {
  __shared__ float o_lds[2][4][16][OP];
  __shared__ float ml_lds[2][4][2][16];

  const int tid  = threadIdx.x;
  const int wave = tid >> 6;
  const int lane = tid & 63;
  const int l16  = lane & 15;
  const int lq   = lane >> 4;
  const int bid  = blockIdx.x;
  const int b    = bid & 7;           // batch -> XCD pin
  const int pidx = bid >> 3;          // 0..127
  const int qtA  = pidx;
  const int qtB  = 255 - pidx;

  const size_t bT = (size_t)b * SEQ;
  const short* kbase = kb + bT * HDIM + lq * 8;
  const short* vrow0 = vT + ((size_t)b * HDIM + l16) * SEQ;

  // ---- tile A (partials straight to LDS to keep register peak low) ----
  {
    float mA = -1e30f, lA = 0.f;
    f32x4 oA[4];
    #pragma unroll
    for (int j = 0; j < 4; ++j) oA[j] = zero4();
    process_tile(qb, kbase, vrow0, bT, qtA, wave, l16, lq, mA, lA, oA);
    #pragma unroll
    for (int j4 = 0; j4 < 4; ++j4) {
      float4 a;
      a.x = oA[j4][0]; a.y = oA[j4][1]; a.z = oA[j4][2]; a.w = oA[j4][3];
      *(float4*)&o_lds[0][wave][l16][j4 * 16 + lq * 4] = a;
    }
    if (lq == 0) {
      ml_lds[0][wave][0][l16] = mA; ml_lds[0][wave][1][l16] = lA;
    }
  }

  // ---- tile B ----
  {
    float mB = -1e30f, lB = 0.f;
    f32x4 oB[4];
    #pragma unroll
    for (int j = 0; j < 4; ++j) oB[j] = zero4();
    process_tile(qb, kbase, vrow0, bT, qtB, wave, l16, lq, mB, lB, oB);
    #pragma unroll
    for (int j4 = 0; j4 < 4; ++j4) {
      float4 c;
      c.x = oB[j4][0]; c.y = oB[j4][1]; c.z = oB[j4][2]; c.w = oB[j4][3];
      *(float4*)&o_lds[1][wave][l16][j4 * 16 + lq * 4] = c;
    }
    if (lq == 0) {
      ml_lds[1][wave][0][l16] = mB; ml_lds[1][wave][1][l16] = lB;
    }
  }
  __syncthreads();

  // ---- merge: wave w -> tile w>>1, rows (w&1)*8 + lane>>3 ----
  const int t    = wave >> 1;
  const int row  = ((wave & 1) << 3) + (lane >> 3);
  const int col0 = (lane & 7) << 3;
  const int qt_t = t ? qtB : qtA;

  float m0 = ml_lds[t][0][0][row], m1 = ml_lds[t][1][0][row];
  float m2 = ml_lds[t][2][0][row], m3 = ml_lds[t][3][0][row];
  float mm = fmaxf(fmaxf(m0, m1), fmaxf(m2, m3));
  float w0 = exp2f(m0 - mm), w1 = exp2f(m1 - mm);
  float w2 = exp2f(m2 - mm), w3 = exp2f(m3 - mm);
  float ls = w0 * ml_lds[t][0][1][row] + w1 * ml_lds[t][1][1][row]
           + w2 * ml_lds[t][2][1][row] + w3 * ml_lds[t][3][1][row];

  float acc[8];
  #pragma unroll
  for (int c = 0; c < 8; ++c) acc[c] = 0.f;
  const float wgt[4] = {w0, w1, w2, w3};
  #pragma unroll
  for (int p = 0; p < 4; ++p) {
    float4 a = *(float4*)&o_lds[t][p][row][col0];
    float4 c = *(float4*)&o_lds[t][p][row][col0 + 4];
    acc[0] += wgt[p] * a.x; acc[1] += wgt[p] * a.y;
    acc[2] += wgt[p] * a.z; acc[3] += wgt[p] * a.w;
    acc[4] += wgt[p] * c.x; acc[5] += wgt[p] * c.y;
    acc[6] += wgt[p] * c.z; acc[7] += wgt[p] * c.w;
  }
  const float inv = 1.0f / ls;
  float4 r0, r1;
  r0.x = acc[0] * inv; r0.y = acc[1] * inv; r0.z = acc[2] * inv; r0.w = acc[3] * inv;
  r1.x = acc[4] * inv; r1.y = acc[5] * inv; r1.z = acc[6] * inv; r1.w = acc[7] * inv;
  float* orow = out + (bT + (size_t)qt_t * 16 + row) * HDIM + col0;
  *(float4*)orow       = r0;
  *(float4*)(orow + 4) = r1;
}

// ---------------------------------------------------------------------------
extern "C" void kernel_launch(void* const* d_in, const int* in_sizes, int n_in,
                              void* d_out, int out_size, void* d_ws, size_t ws_size,
                              hipStream_t stream) {
  (void)in_sizes; (void)n_in; (void)out_size; (void)ws_size;
  const float* x  = (const float*)d_in[0];
  const float* Wq = (const float*)d_in[1];
  const float* Wk = (const float*)d_in[2];
  const float* Wv = (const float*)d_in[3];

  const size_t qkvb = (size_t)BATCH * SEQ * HDIM * sizeof(short);  // 4 MB each
  char* ws = (char*)d_ws;
  short* qb = (short*)(ws);
  short* kb = (short*)(ws + qkvb);
  short* vT = (short*)(ws + 2 * qkvb);
  short* Wt = (short*)(ws + 3 * qkvb);

  wpack_kernel<<<dim3((192 * CDIM + 255) / 256), dim3(256), 0, stream>>>(Wq, Wk, Wv, Wt);
  qkv_kernel<<<dim3(BATCH * SEQ / 64), dim3(256), 0, stream>>>(x, Wt, qb, kb, vT);
  attn_kernel<<<dim3(1024), dim3(256), 0, stream>>>(qb, kb, vT, (float*)d_out);
}

// Round 5
// 101.199 us; speedup vs baseline: 2.4668x; 2.0924x over previous
//
#include <hip/hip_runtime.h>
#include <hip/hip_bf16.h>
#include <cstdint>
#include <cstddef>

#define BATCH 8
#define SEQ   4096
#define CDIM  384
#define HDIM  64

typedef __attribute__((ext_vector_type(8))) __bf16 bf16x8;
typedef __attribute__((ext_vector_type(4))) float  f32x4;
typedef __attribute__((ext_vector_type(4))) short  short4v;

#if __has_builtin(__builtin_amdgcn_mfma_f32_16x16x16bf16_1k)
#define HAVE_MFMA161616 1
#else
#define HAVE_MFMA161616 0
#endif

typedef __attribute__((address_space(3))) char lds_char;
typedef const __attribute__((address_space(1))) char gbl_char;

static __device__ __forceinline__ void gl_lds16(const void* g, void* l) {
  __builtin_amdgcn_global_load_lds((gbl_char*)g, (lds_char*)l, 16, 0, 0);
}

static __device__ __forceinline__ short f2bf(float f) {
  union { float f; uint32_t u; } v; v.f = f;
  uint32_t r = v.u + 0x7fffu + ((v.u >> 16) & 1u);
  return (short)(r >> 16);
}

static __device__ __forceinline__ f32x4 mfma16(bf16x8 a, bf16x8 b, f32x4 c) {
  return __builtin_amdgcn_mfma_f32_16x16x32_bf16(a, b, c, 0, 0, 0);
}

static __device__ __forceinline__ f32x4 zero4() {
  f32x4 z = {0.f, 0.f, 0.f, 0.f};
  return z;
}

// ---------------------------------------------------------------------------
// Pack Wq|Wk|Wv into Wt [192][384] bf16 (transposed, K contiguous).  Wq is
// prescaled by 0.125*log2(e): softmax runs in base 2 with no extra multiply.
// ---------------------------------------------------------------------------
__global__ __launch_bounds__(256) void wpack_kernel(
    const float* __restrict__ Wq, const float* __restrict__ Wk,
    const float* __restrict__ Wv, short* __restrict__ Wt) {
  int idx = blockIdx.x * 256 + threadIdx.x;
  if (idx >= 192 * CDIM) return;
  int n = idx / CDIM;
  int c = idx - n * CDIM;
  int m = n >> 6, h = n & 63;
  const float* W = (m == 0) ? Wq : (m == 1) ? Wk : Wv;
  float s = (m == 0) ? 0.18033688011112042f : 1.0f;  // 0.125 * log2(e)
  Wt[idx] = f2bf(W[c * HDIM + h] * s);
}

// ---------------------------------------------------------------------------
// QKV projection: x [32768][384] f32 -> q,k [b][t][64] bf16, v transposed
// vT [b][64][t] bf16.
// ---------------------------------------------------------------------------
#define XPAD 392

__global__ __launch_bounds__(256) void qkv_kernel(
    const float* __restrict__ x, const short* __restrict__ Wt,
    short* __restrict__ qb, short* __restrict__ kb, short* __restrict__ vT) {
  __shared__ short xs[64 * XPAD];
  const int tid = threadIdx.x;
  const int tokbase = blockIdx.x * 64;

  const float4* xg = (const float4*)(x + (size_t)tokbase * CDIM);
  for (int it = tid; it < 64 * (CDIM / 4); it += 256) {
    int r  = it / (CDIM / 4);
    int c4 = it - r * (CDIM / 4);
    float4 v = xg[it];
    short4v s;
    s[0] = f2bf(v.x); s[1] = f2bf(v.y); s[2] = f2bf(v.z); s[3] = f2bf(v.w);
    *(short4v*)&xs[r * XPAD + c4 * 4] = s;
  }
  __syncthreads();

  const int wave = tid >> 6;
  const int lane = tid & 63;
  const int l16  = lane & 15;
  const int lq   = lane >> 4;

  f32x4 acc[4][3];
  #pragma unroll
  for (int ai = 0; ai < 4; ++ai)
    #pragma unroll
    for (int j = 0; j < 3; ++j) acc[ai][j] = zero4();

  #pragma unroll 2
  for (int kk = 0; kk < CDIM / 32; ++kk) {
    const int k0 = kk * 32;
    bf16x8 a[4];
    #pragma unroll
    for (int ai = 0; ai < 4; ++ai)
      a[ai] = *(const bf16x8*)&xs[(ai * 16 + l16) * XPAD + k0 + lq * 8];
    bf16x8 bb[3];
    #pragma unroll
    for (int j = 0; j < 3; ++j) {
      const int nt = wave * 3 + j;
      bb[j] = *(const bf16x8*)&Wt[(size_t)(nt * 16 + l16) * CDIM + k0 + lq * 8];
    }
    #pragma unroll
    for (int ai = 0; ai < 4; ++ai)
      #pragma unroll
      for (int j = 0; j < 3; ++j)
        acc[ai][j] = mfma16(a[ai], bb[j], acc[ai][j]);
  }

  const int b     = tokbase >> 12;
  const int tloc0 = tokbase & (SEQ - 1);
  #pragma unroll
  for (int j = 0; j < 3; ++j) {
    const int col = (wave * 3 + j) * 16 + l16;
    const int mat = col >> 6;
    const int h   = col & 63;
    #pragma unroll
    for (int ai = 0; ai < 4; ++ai) {
      const int row0 = ai * 16 + lq * 4;
      if (mat < 2) {
        short* dst = mat ? kb : qb;
        #pragma unroll
        for (int r = 0; r < 4; ++r)
          dst[(size_t)(tokbase + row0 + r) * HDIM + h] = f2bf(acc[ai][j][r]);
      } else {
        short4v s;
        #pragma unroll
        for (int r = 0; r < 4; ++r) s[r] = f2bf(acc[ai][j][r]);
        *(short4v*)&vT[(size_t)(b * HDIM + h) * SEQ + (tloc0 + row0)] = s;
      }
    }
  }
}

// ---------------------------------------------------------------------------
// Causal flash attention, block-cooperative LDS staging.
// Block = 64-q-row tile (4 waves x 16 rows), all waves share each 64-s K/V
// tile staged into LDS (global_load_lds w16, double-buffered, XOR-swizzled
// st_16-style: LDS linear dest + pre-swizzled GLOBAL src + swizzled ds_read).
// Static complementary pairing: block i<256 -> qt=63-(i>>3), i>=256 ->
// qt=(i-256)>>3, so co-resident pairs sum to exactly 66 iters.
// ---------------------------------------------------------------------------
__global__ __launch_bounds__(256, 2) void attn_kernel(
    const short* __restrict__ qb, const short* __restrict__ kb,
    const short* __restrict__ vT, float* __restrict__ out) {
  __shared__ short kvbuf[2][2][4096];  // [dbuf][K|V][64 rows x 128B], 32 KB

  const int tid  = threadIdx.x;
  const int wave = tid >> 6;
  const int lane = tid & 63;
  const int l16  = lane & 15;
  const int lq   = lane >> 4;
  const int bid  = blockIdx.x;
  const int half = bid >> 8;
  const int sub  = bid & 255;
  const int b    = sub & 7;            // batch -> XCD spread
  const int idx  = sub >> 3;           // 0..31
  const int qt   = half ? idx : 63 - idx;
  const int q0   = qt << 6;
  const int nkv  = qt + 1;
  const size_t bT = (size_t)b * SEQ;

  const char* kg = (const char*)(kb + bT * HDIM);               // 128B rows
  const char* vg = (const char*)(vT + (size_t)b * HDIM * SEQ);  // 8192B rows

  // staging lane constants: dest is linear (HW: base + lane*16); source col
  // pre-swizzled so that LDS holds phys(r,c) = r*128 + (c ^ ((r&7)<<4)).
  const int rsub = lane >> 3;                 // row within 8-row group
  const int gcol = ((lane & 7) << 4) ^ (rsub << 4);
  const int krb  = wave * 16;                 // this wave's 16 rows of tile

  // Q fragments (prescaled by 0.125*log2e at wpack)
  bf16x8 qf0, qf1;
  {
    const short* qrow = qb + (bT + q0 + wave * 16 + l16) * HDIM + lq * 8;
    qf0 = *(const bf16x8*)qrow;
    qf1 = *(const bf16x8*)(qrow + 32);
  }

  f32x4 oacc[4];
  #pragma unroll
  for (int j = 0; j < 4; ++j) oacc[j] = zero4();
  float m = -1e30f, l = 0.f;

  // loop-invariant swizzled read offsets
  const int swz   = (l16 & 7) << 4;
  const int koff0 = (lq * 16) ^ swz;
  const int koff1 = (64 + lq * 16) ^ swz;

  // prologue: stage tile 0
  #pragma unroll
  for (int i = 0; i < 2; ++i) {
    const int r = krb + i * 8;
    gl_lds16(kg + (size_t)(r + rsub) * 128 + gcol,
             (char*)&kvbuf[0][0][0] + r * 128);
    gl_lds16(vg + (size_t)(r + rsub) * 8192 + gcol,
             (char*)&kvbuf[0][1][0] + r * 128);
  }
  __syncthreads();

  int cur = 0;
  for (int it = 0; it < nkv; ++it) {
    const int s0 = it << 6;
    if (it + 1 < nkv) {  // stage next tile into other buffer (async)
      const int s1 = s0 + 64;
      const int nb = cur ^ 1;
      #pragma unroll
      for (int i = 0; i < 2; ++i) {
        const int r = krb + i * 8;
        gl_lds16(kg + (size_t)(s1 + r + rsub) * 128 + gcol,
                 (char*)&kvbuf[nb][0][0] + r * 128);
        gl_lds16(vg + (size_t)(r + rsub) * 8192 + (size_t)s1 * 2 + gcol,
                 (char*)&kvbuf[nb][1][0] + r * 128);
      }
    }

    const char* kbt = (const char*)&kvbuf[cur][0][0];
    const char* vbt = (const char*)&kvbuf[cur][1][0];

    // S^T = mfma(K, Q): sacc[n][r] = S[q=l16][s = s0 + n*16 + lq*4 + r]
    f32x4 sacc[4];
    #pragma unroll
    for (int n = 0; n < 4; ++n) {
      bf16x8 k0 = *(const bf16x8*)(kbt + (n * 16 + l16) * 128 + koff0);
      bf16x8 k1 = *(const bf16x8*)(kbt + (n * 16 + l16) * 128 + koff1);
      sacc[n] = mfma16(k0, qf0, zero4());
      sacc[n] = mfma16(k1, qf1, sacc[n]);
    }

    // causal mask: only the diagonal tile (it == nkv-1 is s0 == q0)
    if (it == nkv - 1) {
      const int qg = q0 + wave * 16 + l16;
      #pragma unroll
      for (int n = 0; n < 4; ++n) {
        const int sg = s0 + n * 16 + lq * 4;
        #pragma unroll
        for (int r = 0; r < 4; ++r)
          if (sg + r > qg) sacc[n][r] = -1e30f;
      }
    }

    // per-q max: register tree + 2 shfl_xor across lq
    float pm;
    {
      float t0 = fmaxf(fmaxf(sacc[0][0], sacc[0][1]), fmaxf(sacc[0][2], sacc[0][3]));
      float t1 = fmaxf(fmaxf(sacc[1][0], sacc[1][1]), fmaxf(sacc[1][2], sacc[1][3]));
      float t2 = fmaxf(fmaxf(sacc[2][0], sacc[2][1]), fmaxf(sacc[2][2], sacc[2][3]));
      float t3 = fmaxf(fmaxf(sacc[3][0], sacc[3][1]), fmaxf(sacc[3][2], sacc[3][3]));
      pm = fmaxf(fmaxf(t0, t1), fmaxf(t2, t3));
    }
    pm = fmaxf(pm, __shfl_xor(pm, 16, 64));
    pm = fmaxf(pm, __shfl_xor(pm, 32, 64));

    // defer-max rescale (T13)
    if (!__all(pm <= m)) {
      const float mn = fmaxf(m, pm);
      const float sc = exp2f(m - mn);
      m = mn; l *= sc;
      #pragma unroll
      for (int j = 0; j < 4; ++j)
        #pragma unroll
        for (int r = 0; r < 4; ++r) oacc[j][r] *= sc;
    }

    // P = 2^(S - m), row sum
    float p[4][4];
    #pragma unroll
    for (int n = 0; n < 4; ++n)
      #pragma unroll
      for (int r = 0; r < 4; ++r) p[n][r] = exp2f(sacc[n][r] - m);
    float rs = ((p[0][0] + p[0][1]) + (p[0][2] + p[0][3]))
             + ((p[1][0] + p[1][1]) + (p[1][2] + p[1][3]))
             + ((p[2][0] + p[2][1]) + (p[2][2] + p[2][3]))
             + ((p[3][0] + p[3][1]) + (p[3][2] + p[3][3]));
    rs += __shfl_xor(rs, 16, 64);
    rs += __shfl_xor(rs, 32, 64);
    l += rs;

    uint32_t w32[4][2];
    #pragma unroll
    for (int n = 0; n < 4; ++n)
      #pragma unroll
      for (int c = 0; c < 2; ++c)
        asm("v_cvt_pk_bf16_f32 %0, %1, %2"
            : "=v"(w32[n][c]) : "v"(p[n][2 * c]), "v"(p[n][2 * c + 1]));

    // O^T += V^T P^T  (V from LDS, swizzled reads)
#if HAVE_MFMA161616
    short4v pb[4];
    #pragma unroll
    for (int n = 0; n < 4; ++n) {
      union { uint32_t u[2]; short4v s; } t;
      t.u[0] = w32[n][0]; t.u[1] = w32[n][1];
      pb[n] = t.s;
    }
    #pragma unroll
    for (int j = 0; j < 4; ++j) {
      const char* vr = vbt + (j * 16 + l16) * 128;
      #pragma unroll
      for (int n = 0; n < 4; ++n) {
        short4v vfn = *(const short4v*)(vr + ((n * 32 + lq * 8) ^ swz));
        oacc[j] = __builtin_amdgcn_mfma_f32_16x16x16bf16_1k(vfn, pb[n],
                                                            oacc[j], 0, 0, 0);
      }
    }
#else
    union { uint32_t u[4]; bf16x8 v; } pf0, pf1;
    #pragma unroll
    for (int aa = 0; aa < 4; ++aa) {
      const int src = l16 + ((((lq << 1) + (aa >> 1)) & 3) << 4);
      uint32_t lo0 = (uint32_t)__shfl((int)w32[0][aa & 1], src, 64);
      uint32_t hi0 = (uint32_t)__shfl((int)w32[1][aa & 1], src, 64);
      uint32_t lo1 = (uint32_t)__shfl((int)w32[2][aa & 1], src, 64);
      uint32_t hi1 = (uint32_t)__shfl((int)w32[3][aa & 1], src, 64);
      pf0.u[aa] = (lq & 2) ? hi0 : lo0;
      pf1.u[aa] = (lq & 2) ? hi1 : lo1;
    }
    #pragma unroll
    for (int j = 0; j < 4; ++j) {
      const char* vr = vbt + (j * 16 + l16) * 128;
      bf16x8 v0 = *(const bf16x8*)(vr + ((lq * 16) ^ swz));
      bf16x8 v1 = *(const bf16x8*)(vr + ((64 + lq * 16) ^ swz));
      oacc[j] = mfma16(v0, pf0.v, oacc[j]);
      oacc[j] = mfma16(v1, pf1.v, oacc[j]);
    }
#endif

    __syncthreads();  // drains vmcnt (incl. staged prefetch) + closes reads
    cur ^= 1;
  }

  const float inv = 1.0f / l;
  #pragma unroll
  for (int j = 0; j < 4; ++j) {
    float4 o;
    o.x = oacc[j][0] * inv; o.y = oacc[j][1] * inv;
    o.z = oacc[j][2] * inv; o.w = oacc[j][3] * inv;
    *(float4*)&out[(bT + q0 + wave * 16 + l16) * HDIM + j * 16 + lq * 4] = o;
  }
}

// ---------------------------------------------------------------------------
extern "C" void kernel_launch(void* const* d_in, const int* in_sizes, int n_in,
                              void* d_out, int out_size, void* d_ws, size_t ws_size,
                              hipStream_t stream) {
  (void)in_sizes; (void)n_in; (void)out_size; (void)ws_size;
  const float* x  = (const float*)d_in[0];
  const float* Wq = (const float*)d_in[1];
  const float* Wk = (const float*)d_in[2];
  const float* Wv = (const float*)d_in[3];

  const size_t qkvb = (size_t)BATCH * SEQ * HDIM * sizeof(short);  // 4 MB each
  char* ws = (char*)d_ws;
  short* qb = (short*)(ws);
  short* kb = (short*)(ws + qkvb);
  short* vT = (short*)(ws + 2 * qkvb);
  short* Wt = (short*)(ws + 3 * qkvb);

  wpack_kernel<<<dim3((192 * CDIM + 255) / 256), dim3(256), 0, stream>>>(Wq, Wk, Wv, Wt);
  qkv_kernel<<<dim3(BATCH * SEQ / 64), dim3(256), 0, stream>>>(x, Wt, qb, kb, vT);
  attn_kernel<<<dim3(512), dim3(256), 0, stream>>>(qb, kb, vT, (float*)d_out);
}

// Round 6
// 81.512 us; speedup vs baseline: 3.0626x; 1.2415x over previous
//
#include <hip/hip_runtime.h>
#include <hip/hip_bf16.h>
#include <cstdint>
#include <cstddef>

#define BATCH 8
#define SEQ   4096
#define CDIM  384
#define HDIM  64

typedef __attribute__((ext_vector_type(8))) __bf16 bf16x8;
typedef __attribute__((ext_vector_type(4))) float  f32x4;
typedef __attribute__((ext_vector_type(4))) short  short4v;

#if __has_builtin(__builtin_amdgcn_mfma_f32_16x16x16bf16_1k)
#define HAVE_MFMA161616 1
#else
#define HAVE_MFMA161616 0
#endif

typedef __attribute__((address_space(3))) char lds_char;
typedef const __attribute__((address_space(1))) char gbl_char;

static __device__ __forceinline__ void gl_lds16(const void* g, void* l) {
  __builtin_amdgcn_global_load_lds((gbl_char*)g, (lds_char*)l, 16, 0, 0);
}

static __device__ __forceinline__ short f2bf(float f) {
  union { float f; uint32_t u; } v; v.f = f;
  uint32_t r = v.u + 0x7fffu + ((v.u >> 16) & 1u);
  return (short)(r >> 16);
}

static __device__ __forceinline__ f32x4 mfma16(bf16x8 a, bf16x8 b, f32x4 c) {
  return __builtin_amdgcn_mfma_f32_16x16x32_bf16(a, b, c, 0, 0, 0);
}

static __device__ __forceinline__ f32x4 zero4() {
  f32x4 z = {0.f, 0.f, 0.f, 0.f};
  return z;
}

// ---------------------------------------------------------------------------
// Pack Wq|Wk|Wv into Wt [192][384] bf16 (transposed, K contiguous).  Wq is
// prescaled by 0.125*log2(e): softmax runs in base 2 with no extra multiply.
// ---------------------------------------------------------------------------
__global__ __launch_bounds__(256) void wpack_kernel(
    const float* __restrict__ Wq, const float* __restrict__ Wk,
    const float* __restrict__ Wv, short* __restrict__ Wt) {
  int idx = blockIdx.x * 256 + threadIdx.x;
  if (idx >= 192 * CDIM) return;
  int n = idx / CDIM;
  int c = idx - n * CDIM;
  int m = n >> 6, h = n & 63;
  const float* W = (m == 0) ? Wq : (m == 1) ? Wk : Wv;
  float s = (m == 0) ? 0.18033688011112042f : 1.0f;  // 0.125 * log2(e)
  Wt[idx] = f2bf(W[c * HDIM + h] * s);
}

// ---------------------------------------------------------------------------
// QKV projection: x [32768][384] f32 -> q,k [b][t][64] bf16, v transposed
// vT [b][64][t] bf16.
// ---------------------------------------------------------------------------
#define XPAD 392

__global__ __launch_bounds__(256) void qkv_kernel(
    const float* __restrict__ x, const short* __restrict__ Wt,
    short* __restrict__ qb, short* __restrict__ kb, short* __restrict__ vT) {
  __shared__ short xs[64 * XPAD];
  const int tid = threadIdx.x;
  const int tokbase = blockIdx.x * 64;

  const float4* xg = (const float4*)(x + (size_t)tokbase * CDIM);
  for (int it = tid; it < 64 * (CDIM / 4); it += 256) {
    int r  = it / (CDIM / 4);
    int c4 = it - r * (CDIM / 4);
    float4 v = xg[it];
    short4v s;
    s[0] = f2bf(v.x); s[1] = f2bf(v.y); s[2] = f2bf(v.z); s[3] = f2bf(v.w);
    *(short4v*)&xs[r * XPAD + c4 * 4] = s;
  }
  __syncthreads();

  const int wave = tid >> 6;
  const int lane = tid & 63;
  const int l16  = lane & 15;
  const int lq   = lane >> 4;

  f32x4 acc[4][3];
  #pragma unroll
  for (int ai = 0; ai < 4; ++ai)
    #pragma unroll
    for (int j = 0; j < 3; ++j) acc[ai][j] = zero4();

  #pragma unroll 2
  for (int kk = 0; kk < CDIM / 32; ++kk) {
    const int k0 = kk * 32;
    bf16x8 a[4];
    #pragma unroll
    for (int ai = 0; ai < 4; ++ai)
      a[ai] = *(const bf16x8*)&xs[(ai * 16 + l16) * XPAD + k0 + lq * 8];
    bf16x8 bb[3];
    #pragma unroll
    for (int j = 0; j < 3; ++j) {
      const int nt = wave * 3 + j;
      bb[j] = *(const bf16x8*)&Wt[(size_t)(nt * 16 + l16) * CDIM + k0 + lq * 8];
    }
    #pragma unroll
    for (int ai = 0; ai < 4; ++ai)
      #pragma unroll
      for (int j = 0; j < 3; ++j)
        acc[ai][j] = mfma16(a[ai], bb[j], acc[ai][j]);
  }

  const int b     = tokbase >> 12;
  const int tloc0 = tokbase & (SEQ - 1);
  #pragma unroll
  for (int j = 0; j < 3; ++j) {
    const int col = (wave * 3 + j) * 16 + l16;
    const int mat = col >> 6;
    const int h   = col & 63;
    #pragma unroll
    for (int ai = 0; ai < 4; ++ai) {
      const int row0 = ai * 16 + lq * 4;
      if (mat < 2) {
        short* dst = mat ? kb : qb;
        #pragma unroll
        for (int r = 0; r < 4; ++r)
          dst[(size_t)(tokbase + row0 + r) * HDIM + h] = f2bf(acc[ai][j][r]);
      } else {
        short4v s;
        #pragma unroll
        for (int r = 0; r < 4; ++r) s[r] = f2bf(acc[ai][j][r]);
        *(short4v*)&vT[(size_t)(b * HDIM + h) * SEQ + (tloc0 + row0)] = s;
      }
    }
  }
}

// ---------------------------------------------------------------------------
// Causal flash attention, KV-split (flash-decoding style).
// 1024 blocks: bid&7 = batch, idx=bid>>3 in [0,128): qt = 63-(idx>>1),
// half = idx&1.  Lower half covers s-tiles [0,n0), upper [n0,nkv) where
// n0 = qt/2+1 -> chunk sizes descend with bid (greedy LPT balancing).
// Each block: 64-q-row tile, 4 waves, K/V staged to LDS (global_load_lds w16,
// double-buffered, XOR-swizzled via pre-swizzled global source).
// Half0 writes unnormalized partials to OUT, half1 to OPART; m,l to MLW.
// merge_kernel renormalizes.
// ---------------------------------------------------------------------------
__global__ __launch_bounds__(256, 2) void attn_kernel(
    const short* __restrict__ qb, const short* __restrict__ kb,
    const short* __restrict__ vT, float* __restrict__ out,
    float* __restrict__ opart, float2* __restrict__ mlw) {
  __shared__ short kvbuf[2][2][4096];  // [dbuf][K|V][64 rows x 128B], 32 KB

  const int tid  = threadIdx.x;
  const int wave = tid >> 6;
  const int lane = tid & 63;
  const int l16  = lane & 15;
  const int lq   = lane >> 4;
  const int bid  = blockIdx.x;
  const int b    = bid & 7;            // batch -> XCD spread
  const int idx  = bid >> 3;           // 0..127
  const int qt   = 63 - (idx >> 1);
  const int half = idx & 1;
  const int nkv  = qt + 1;
  const int n0   = (qt >> 1) + 1;
  const int n1   = nkv - n0;
  const int scnt = half ? n1 : n0;
  const int sbeg = half ? n0 : 0;
  const bool dia = half ? (n1 > 0) : (n1 == 0);
  const int q0   = qt << 6;
  const size_t bT = (size_t)b * SEQ;

  const char* kg = (const char*)(kb + bT * HDIM);               // 128B rows
  const char* vg = (const char*)(vT + (size_t)b * HDIM * SEQ);  // 8192B rows

  // staging lane constants: dest linear (base + lane*16); source col
  // pre-swizzled so LDS holds phys(r,c) = r*128 + (c ^ ((r&7)<<4)).
  const int rsub = lane >> 3;
  const int gcol = ((lane & 7) << 4) ^ (rsub << 4);
  const int krb  = wave * 16;

  f32x4 oacc[4];
  #pragma unroll
  for (int j = 0; j < 4; ++j) oacc[j] = zero4();
  float m = -1e30f, l = 0.f;

  if (scnt > 0) {
    // Q fragments (prescaled by 0.125*log2e at wpack)
    bf16x8 qf0, qf1;
    {
      const short* qrow = qb + (bT + q0 + wave * 16 + l16) * HDIM + lq * 8;
      qf0 = *(const bf16x8*)qrow;
      qf1 = *(const bf16x8*)(qrow + 32);
    }

    const int swz   = (l16 & 7) << 4;
    const int koff0 = (lq * 16) ^ swz;
    const int koff1 = (64 + lq * 16) ^ swz;

    // prologue: stage first tile
    {
      const int sf = sbeg << 6;
      #pragma unroll
      for (int i = 0; i < 2; ++i) {
        const int r = krb + i * 8;
        gl_lds16(kg + (size_t)(sf + r + rsub) * 128 + gcol,
                 (char*)&kvbuf[0][0][0] + r * 128);
        gl_lds16(vg + (size_t)(r + rsub) * 8192 + (size_t)sf * 2 + gcol,
                 (char*)&kvbuf[0][1][0] + r * 128);
      }
    }
    __syncthreads();

    int cur = 0;
    for (int it = 0; it < scnt; ++it) {
      const int s0 = (sbeg + it) << 6;
      if (it + 1 < scnt) {  // stage next tile into other buffer (async)
        const int s1 = s0 + 64;
        const int nb = cur ^ 1;
        #pragma unroll
        for (int i = 0; i < 2; ++i) {
          const int r = krb + i * 8;
          gl_lds16(kg + (size_t)(s1 + r + rsub) * 128 + gcol,
                   (char*)&kvbuf[nb][0][0] + r * 128);
          gl_lds16(vg + (size_t)(r + rsub) * 8192 + (size_t)s1 * 2 + gcol,
                   (char*)&kvbuf[nb][1][0] + r * 128);
        }
      }

      const char* kbt = (const char*)&kvbuf[cur][0][0];
      const char* vbt = (const char*)&kvbuf[cur][1][0];

      // S^T = mfma(K, Q): sacc[n][r] = S[q=l16][s = s0 + n*16 + lq*4 + r]
      f32x4 sacc[4];
      #pragma unroll
      for (int n = 0; n < 4; ++n) {
        bf16x8 k0 = *(const bf16x8*)(kbt + (n * 16 + l16) * 128 + koff0);
        bf16x8 k1 = *(const bf16x8*)(kbt + (n * 16 + l16) * 128 + koff1);
        sacc[n] = mfma16(k0, qf0, zero4());
        sacc[n] = mfma16(k1, qf1, sacc[n]);
      }

      // causal mask: only the diagonal tile
      if (dia && it == scnt - 1) {
        const int qg = q0 + wave * 16 + l16;
        #pragma unroll
        for (int n = 0; n < 4; ++n) {
          const int sg = s0 + n * 16 + lq * 4;
          #pragma unroll
          for (int r = 0; r < 4; ++r)
            if (sg + r > qg) sacc[n][r] = -1e30f;
        }
      }

      // per-q max: register tree + 2 shfl_xor across lq
      float pm;
      {
        float t0 = fmaxf(fmaxf(sacc[0][0], sacc[0][1]), fmaxf(sacc[0][2], sacc[0][3]));
        float t1 = fmaxf(fmaxf(sacc[1][0], sacc[1][1]), fmaxf(sacc[1][2], sacc[1][3]));
        float t2 = fmaxf(fmaxf(sacc[2][0], sacc[2][1]), fmaxf(sacc[2][2], sacc[2][3]));
        float t3 = fmaxf(fmaxf(sacc[3][0], sacc[3][1]), fmaxf(sacc[3][2], sacc[3][3]));
        pm = fmaxf(fmaxf(t0, t1), fmaxf(t2, t3));
      }
      pm = fmaxf(pm, __shfl_xor(pm, 16, 64));
      pm = fmaxf(pm, __shfl_xor(pm, 32, 64));

      // defer-max rescale (T13)
      if (!__all(pm <= m)) {
        const float mn = fmaxf(m, pm);
        const float sc = exp2f(m - mn);
        m = mn; l *= sc;
        #pragma unroll
        for (int j = 0; j < 4; ++j)
          #pragma unroll
          for (int r = 0; r < 4; ++r) oacc[j][r] *= sc;
      }

      // P = 2^(S - m), row sum
      float p[4][4];
      #pragma unroll
      for (int n = 0; n < 4; ++n)
        #pragma unroll
        for (int r = 0; r < 4; ++r) p[n][r] = exp2f(sacc[n][r] - m);
      float rs = ((p[0][0] + p[0][1]) + (p[0][2] + p[0][3]))
               + ((p[1][0] + p[1][1]) + (p[1][2] + p[1][3]))
               + ((p[2][0] + p[2][1]) + (p[2][2] + p[2][3]))
               + ((p[3][0] + p[3][1]) + (p[3][2] + p[3][3]));
      rs += __shfl_xor(rs, 16, 64);
      rs += __shfl_xor(rs, 32, 64);
      l += rs;

      uint32_t w32[4][2];
      #pragma unroll
      for (int n = 0; n < 4; ++n)
        #pragma unroll
        for (int c = 0; c < 2; ++c)
          asm("v_cvt_pk_bf16_f32 %0, %1, %2"
              : "=v"(w32[n][c]) : "v"(p[n][2 * c]), "v"(p[n][2 * c + 1]));

      // O^T += V^T P^T  (V from LDS, swizzled reads)
      __builtin_amdgcn_s_setprio(1);
#if HAVE_MFMA161616
      short4v pb[4];
      #pragma unroll
      for (int n = 0; n < 4; ++n) {
        union { uint32_t u[2]; short4v s; } t;
        t.u[0] = w32[n][0]; t.u[1] = w32[n][1];
        pb[n] = t.s;
      }
      #pragma unroll
      for (int j = 0; j < 4; ++j) {
        const char* vr = vbt + (j * 16 + l16) * 128;
        #pragma unroll
        for (int n = 0; n < 4; ++n) {
          short4v vfn = *(const short4v*)(vr + ((n * 32 + lq * 8) ^ swz));
          oacc[j] = __builtin_amdgcn_mfma_f32_16x16x16bf16_1k(vfn, pb[n],
                                                              oacc[j], 0, 0, 0);
        }
      }
#else
      union { uint32_t u[4]; bf16x8 v; } pf0, pf1;
      #pragma unroll
      for (int aa = 0; aa < 4; ++aa) {
        const int src = l16 + ((((lq << 1) + (aa >> 1)) & 3) << 4);
        uint32_t lo0 = (uint32_t)__shfl((int)w32[0][aa & 1], src, 64);
        uint32_t hi0 = (uint32_t)__shfl((int)w32[1][aa & 1], src, 64);
        uint32_t lo1 = (uint32_t)__shfl((int)w32[2][aa & 1], src, 64);
        uint32_t hi1 = (uint32_t)__shfl((int)w32[3][aa & 1], src, 64);
        pf0.u[aa] = (lq & 2) ? hi0 : lo0;
        pf1.u[aa] = (lq & 2) ? hi1 : lo1;
      }
      #pragma unroll
      for (int j = 0; j < 4; ++j) {
        const char* vr = vbt + (j * 16 + l16) * 128;
        bf16x8 v0 = *(const bf16x8*)(vr + ((lq * 16) ^ swz));
        bf16x8 v1 = *(const bf16x8*)(vr + ((64 + lq * 16) ^ swz));
        oacc[j] = mfma16(v0, pf0.v, oacc[j]);
        oacc[j] = mfma16(v1, pf1.v, oacc[j]);
      }
#endif
      __builtin_amdgcn_s_setprio(0);

      __syncthreads();  // drains vmcnt (incl. staged prefetch) + closes reads
      cur ^= 1;
    }
  }

  // write unnormalized partials + (m,l); merge_kernel renormalizes
  float* obase = half ? opart : out;
  const int qrow = q0 + wave * 16 + l16;
  #pragma unroll
  for (int j = 0; j < 4; ++j) {
    float4 o;
    o.x = oacc[j][0]; o.y = oacc[j][1]; o.z = oacc[j][2]; o.w = oacc[j][3];
    *(float4*)&obase[(bT + qrow) * HDIM + j * 16 + lq * 4] = o;
  }
  if (lq == 0) {
    float2 ml; ml.x = m; ml.y = l;
    mlw[half * (BATCH * SEQ) + bT + qrow] = ml;
  }
}

// ---------------------------------------------------------------------------
// Merge the two KV-half partials: out = (w0*out + w1*opart) / (w0*l0 + w1*l1)
// ---------------------------------------------------------------------------
__global__ __launch_bounds__(256) void merge_kernel(
    float* __restrict__ out, const float* __restrict__ opart,
    const float2* __restrict__ mlw) {
  const int g   = blockIdx.x * 256 + threadIdx.x;  // 524288
  const int row = g >> 4;
  const int c4  = (g & 15) << 2;
  const float2 ml0 = mlw[row];
  const float2 ml1 = mlw[BATCH * SEQ + row];
  const float mm = fmaxf(ml0.x, ml1.x);
  const float w0 = exp2f(ml0.x - mm);
  const float w1 = exp2f(ml1.x - mm);
  const float inv = 1.0f / (w0 * ml0.y + w1 * ml1.y);
  float4 a = *(const float4*)&out[(size_t)row * HDIM + c4];
  float4 c = *(const float4*)&opart[(size_t)row * HDIM + c4];
  float4 r;
  r.x = (w0 * a.x + w1 * c.x) * inv;
  r.y = (w0 * a.y + w1 * c.y) * inv;
  r.z = (w0 * a.z + w1 * c.z) * inv;
  r.w = (w0 * a.w + w1 * c.w) * inv;
  *(float4*)&out[(size_t)row * HDIM + c4] = r;
}

// ---------------------------------------------------------------------------
extern "C" void kernel_launch(void* const* d_in, const int* in_sizes, int n_in,
                              void* d_out, int out_size, void* d_ws, size_t ws_size,
                              hipStream_t stream) {
  (void)in_sizes; (void)n_in; (void)out_size; (void)ws_size;
  const float* x  = (const float*)d_in[0];
  const float* Wq = (const float*)d_in[1];
  const float* Wk = (const float*)d_in[2];
  const float* Wv = (const float*)d_in[3];

  const size_t qkvb  = (size_t)BATCH * SEQ * HDIM * sizeof(short);  // 4 MB each
  const size_t opb   = (size_t)BATCH * SEQ * HDIM * sizeof(float);  // 8 MB
  char* ws = (char*)d_ws;
  short*  qb    = (short*)(ws);
  short*  kb    = (short*)(ws + qkvb);
  short*  vT    = (short*)(ws + 2 * qkvb);
  float*  opart = (float*)(ws + 3 * qkvb);
  float2* mlw   = (float2*)(ws + 3 * qkvb + opb);                   // 512 KB
  short*  Wt    = (short*)(ws + 3 * qkvb + opb + (size_t)2 * BATCH * SEQ * sizeof(float2));

  wpack_kernel<<<dim3((192 * CDIM + 255) / 256), dim3(256), 0, stream>>>(Wq, Wk, Wv, Wt);
  qkv_kernel<<<dim3(BATCH * SEQ / 64), dim3(256), 0, stream>>>(x, Wt, qb, kb, vT);
  attn_kernel<<<dim3(1024), dim3(256), 0, stream>>>(qb, kb, vT, (float*)d_out, opart, mlw);
  merge_kernel<<<dim3(BATCH * SEQ * HDIM / 4 / 256), dim3(256), 0, stream>>>(
      (float*)d_out, opart, mlw);
}

// Round 7
// 79.947 us; speedup vs baseline: 3.1225x; 1.0196x over previous
//
#include <hip/hip_runtime.h>
#include <hip/hip_bf16.h>
#include <cstdint>
#include <cstddef>

#define BATCH 8
#define SEQ   4096
#define CDIM  384
#define HDIM  64

typedef __attribute__((ext_vector_type(8))) __bf16 bf16x8;
typedef __attribute__((ext_vector_type(4))) float  f32x4;
typedef __attribute__((ext_vector_type(4))) short  short4v;

#if __has_builtin(__builtin_amdgcn_mfma_f32_16x16x16bf16_1k)
#define HAVE_MFMA161616 1
#else
#define HAVE_MFMA161616 0
#endif

typedef __attribute__((address_space(3))) char lds_char;
typedef const __attribute__((address_space(1))) char gbl_char;

static __device__ __forceinline__ void gl_lds16(const void* g, void* l) {
  __builtin_amdgcn_global_load_lds((gbl_char*)g, (lds_char*)l, 16, 0, 0);
}

static __device__ __forceinline__ short f2bf(float f) {
  union { float f; uint32_t u; } v; v.f = f;
  uint32_t r = v.u + 0x7fffu + ((v.u >> 16) & 1u);
  return (short)(r >> 16);
}

static __device__ __forceinline__ uint32_t cvtpk(float lo, float hi) {
  uint32_t r;
  asm("v_cvt_pk_bf16_f32 %0, %1, %2" : "=v"(r) : "v"(lo), "v"(hi));
  return r;
}

static __device__ __forceinline__ f32x4 mfma16(bf16x8 a, bf16x8 b, f32x4 c) {
  return __builtin_amdgcn_mfma_f32_16x16x32_bf16(a, b, c, 0, 0, 0);
}

static __device__ __forceinline__ f32x4 zero4() {
  f32x4 z = {0.f, 0.f, 0.f, 0.f};
  return z;
}

// ---------------------------------------------------------------------------
// Pack Wq|Wk|Wv into Wt [192][384] bf16 (transposed, K contiguous).  Wq is
// prescaled by 0.125*log2(e): softmax runs in base 2 with no extra multiply.
// ---------------------------------------------------------------------------
__global__ __launch_bounds__(256) void wpack_kernel(
    const float* __restrict__ Wq, const float* __restrict__ Wk,
    const float* __restrict__ Wv, short* __restrict__ Wt) {
  int idx = blockIdx.x * 256 + threadIdx.x;
  if (idx >= 192 * CDIM) return;
  int n = idx / CDIM;
  int c = idx - n * CDIM;
  int m = n >> 6, h = n & 63;
  const float* W = (m == 0) ? Wq : (m == 1) ? Wk : Wv;
  float s = (m == 0) ? 0.18033688011112042f : 1.0f;  // 0.125 * log2(e)
  Wt[idx] = f2bf(W[c * HDIM + h] * s);
}

// ---------------------------------------------------------------------------
// QKV projection: x [32768][384] f32 -> q,k [b][t][64] bf16, v transposed
// vT [b][64][t] bf16.  x staged to LDS via v_cvt_pk_bf16_f32.
// ---------------------------------------------------------------------------
#define XPAD 392

__global__ __launch_bounds__(256) void qkv_kernel(
    const float* __restrict__ x, const short* __restrict__ Wt,
    short* __restrict__ qb, short* __restrict__ kb, short* __restrict__ vT) {
  __shared__ short xs[64 * XPAD];
  const int tid = threadIdx.x;
  const int tokbase = blockIdx.x * 64;

  const float4* xg = (const float4*)(x + (size_t)tokbase * CDIM);
  for (int it = tid; it < 64 * (CDIM / 4); it += 256) {
    int r  = it / (CDIM / 4);
    int c4 = it - r * (CDIM / 4);
    float4 v = xg[it];
    uint2 st;
    st.x = cvtpk(v.x, v.y);
    st.y = cvtpk(v.z, v.w);
    *(uint2*)&xs[r * XPAD + c4 * 4] = st;
  }
  __syncthreads();

  const int wave = tid >> 6;
  const int lane = tid & 63;
  const int l16  = lane & 15;
  const int lq   = lane >> 4;

  f32x4 acc[4][3];
  #pragma unroll
  for (int ai = 0; ai < 4; ++ai)
    #pragma unroll
    for (int j = 0; j < 3; ++j) acc[ai][j] = zero4();

  #pragma unroll 2
  for (int kk = 0; kk < CDIM / 32; ++kk) {
    const int k0 = kk * 32;
    bf16x8 a[4];
    #pragma unroll
    for (int ai = 0; ai < 4; ++ai)
      a[ai] = *(const bf16x8*)&xs[(ai * 16 + l16) * XPAD + k0 + lq * 8];
    bf16x8 bb[3];
    #pragma unroll
    for (int j = 0; j < 3; ++j) {
      const int nt = wave * 3 + j;
      bb[j] = *(const bf16x8*)&Wt[(size_t)(nt * 16 + l16) * CDIM + k0 + lq * 8];
    }
    #pragma unroll
    for (int ai = 0; ai < 4; ++ai)
      #pragma unroll
      for (int j = 0; j < 3; ++j)
        acc[ai][j] = mfma16(a[ai], bb[j], acc[ai][j]);
  }

  const int b     = tokbase >> 12;
  const int tloc0 = tokbase & (SEQ - 1);
  #pragma unroll
  for (int j = 0; j < 3; ++j) {
    const int col = (wave * 3 + j) * 16 + l16;
    const int mat = col >> 6;
    const int h   = col & 63;
    #pragma unroll
    for (int ai = 0; ai < 4; ++ai) {
      const int row0 = ai * 16 + lq * 4;
      if (mat < 2) {
        short* dst = mat ? kb : qb;
        #pragma unroll
        for (int r = 0; r < 4; ++r)
          dst[(size_t)(tokbase + row0 + r) * HDIM + h] = f2bf(acc[ai][j][r]);
      } else {
        union { uint32_t u[2]; short4v s; } sv;
        sv.u[0] = cvtpk(acc[ai][j][0], acc[ai][j][1]);
        sv.u[1] = cvtpk(acc[ai][j][2], acc[ai][j][3]);
        *(short4v*)&vT[(size_t)(b * HDIM + h) * SEQ + (tloc0 + row0)] = sv.s;
      }
    }
  }
}

// ---------------------------------------------------------------------------
// Causal flash attention, 4-way KV split (flash-decoding style).
// 2048 blocks: b = bid&7, idx = bid>>3 in [0,256): qt = 63-(idx>>2),
// quarter = idx&3.  Quarter q covers s-tiles [start, start+size) with
// size = base + (q<rem), base = nkv>>2, rem = nkv&3 -> sizes descend with
// bid (greedy LPT).  64-q-row tile, 4 waves, K/V staged to LDS
// (global_load_lds w16, double-buffered, XOR-swizzled global source).
// Quarter 0 writes unnormalized partials to OUT, quarters 1-3 to OPART;
// per-row (m,l) to MLW.  merge_kernel renormalizes.
// ---------------------------------------------------------------------------
__global__ __launch_bounds__(256, 2) void attn_kernel(
    const short* __restrict__ qb, const short* __restrict__ kb,
    const short* __restrict__ vT, float* __restrict__ out,
    float* __restrict__ opart, float2* __restrict__ mlw) {
  __shared__ short kvbuf[2][2][4096];  // [dbuf][K|V][64 rows x 128B], 32 KB

  const int tid  = threadIdx.x;
  const int wave = tid >> 6;
  const int lane = tid & 63;
  const int l16  = lane & 15;
  const int lq   = lane >> 4;
  const int bid  = blockIdx.x;
  const int b    = bid & 7;            // batch -> XCD spread
  const int idx  = bid >> 3;           // 0..255
  const int qt   = 63 - (idx >> 2);
  const int quarter = idx & 3;
  const int nkv  = qt + 1;
  const int base = nkv >> 2;
  const int rem  = nkv & 3;
  const int scnt = base + (quarter < rem ? 1 : 0);
  const int sbeg = quarter * base + (quarter < rem ? quarter : rem);
  const bool dia = (scnt > 0) && (sbeg + scnt == nkv);
  const int q0   = qt << 6;
  const size_t bT = (size_t)b * SEQ;

  const char* kg = (const char*)(kb + bT * HDIM);               // 128B rows
  const char* vg = (const char*)(vT + (size_t)b * HDIM * SEQ);  // 8192B rows

  // staging lane constants: dest linear (base + lane*16); source col
  // pre-swizzled so LDS holds phys(r,c) = r*128 + (c ^ ((r&7)<<4)).
  const int rsub = lane >> 3;
  const int gcol = ((lane & 7) << 4) ^ (rsub << 4);
  const int krb  = wave * 16;

  f32x4 oacc[4];
  #pragma unroll
  for (int j = 0; j < 4; ++j) oacc[j] = zero4();
  float m = -1e30f, l = 0.f;

  if (scnt > 0) {
    // Q fragments (prescaled by 0.125*log2e at wpack)
    bf16x8 qf0, qf1;
    {
      const short* qrow = qb + (bT + q0 + wave * 16 + l16) * HDIM + lq * 8;
      qf0 = *(const bf16x8*)qrow;
      qf1 = *(const bf16x8*)(qrow + 32);
    }

    const int swz   = (l16 & 7) << 4;
    const int koff0 = (lq * 16) ^ swz;
    const int koff1 = (64 + lq * 16) ^ swz;

    // prologue: stage first tile
    {
      const int sf = sbeg << 6;
      #pragma unroll
      for (int i = 0; i < 2; ++i) {
        const int r = krb + i * 8;
        gl_lds16(kg + (size_t)(sf + r + rsub) * 128 + gcol,
                 (char*)&kvbuf[0][0][0] + r * 128);
        gl_lds16(vg + (size_t)(r + rsub) * 8192 + (size_t)sf * 2 + gcol,
                 (char*)&kvbuf[0][1][0] + r * 128);
      }
    }
    __syncthreads();

    int cur = 0;
    for (int it = 0; it < scnt; ++it) {
      const int s0 = (sbeg + it) << 6;
      if (it + 1 < scnt) {  // stage next tile into other buffer (async)
        const int s1 = s0 + 64;
        const int nb = cur ^ 1;
        #pragma unroll
        for (int i = 0; i < 2; ++i) {
          const int r = krb + i * 8;
          gl_lds16(kg + (size_t)(s1 + r + rsub) * 128 + gcol,
                   (char*)&kvbuf[nb][0][0] + r * 128);
          gl_lds16(vg + (size_t)(r + rsub) * 8192 + (size_t)s1 * 2 + gcol,
                   (char*)&kvbuf[nb][1][0] + r * 128);
        }
      }

      const char* kbt = (const char*)&kvbuf[cur][0][0];
      const char* vbt = (const char*)&kvbuf[cur][1][0];

      // S^T = mfma(K, Q): sacc[n][r] = S[q=l16][s = s0 + n*16 + lq*4 + r]
      f32x4 sacc[4];
      #pragma unroll
      for (int n = 0; n < 4; ++n) {
        bf16x8 k0 = *(const bf16x8*)(kbt + (n * 16 + l16) * 128 + koff0);
        bf16x8 k1 = *(const bf16x8*)(kbt + (n * 16 + l16) * 128 + koff1);
        sacc[n] = mfma16(k0, qf0, zero4());
        sacc[n] = mfma16(k1, qf1, sacc[n]);
      }

      // causal mask: only the diagonal tile
      if (dia && it == scnt - 1) {
        const int qg = q0 + wave * 16 + l16;
        #pragma unroll
        for (int n = 0; n < 4; ++n) {
          const int sg = s0 + n * 16 + lq * 4;
          #pragma unroll
          for (int r = 0; r < 4; ++r)
            if (sg + r > qg) sacc[n][r] = -1e30f;
        }
      }

      // per-q max: register tree + 2 shfl_xor across lq
      float pm;
      {
        float t0 = fmaxf(fmaxf(sacc[0][0], sacc[0][1]), fmaxf(sacc[0][2], sacc[0][3]));
        float t1 = fmaxf(fmaxf(sacc[1][0], sacc[1][1]), fmaxf(sacc[1][2], sacc[1][3]));
        float t2 = fmaxf(fmaxf(sacc[2][0], sacc[2][1]), fmaxf(sacc[2][2], sacc[2][3]));
        float t3 = fmaxf(fmaxf(sacc[3][0], sacc[3][1]), fmaxf(sacc[3][2], sacc[3][3]));
        pm = fmaxf(fmaxf(t0, t1), fmaxf(t2, t3));
      }
      pm = fmaxf(pm, __shfl_xor(pm, 16, 64));
      pm = fmaxf(pm, __shfl_xor(pm, 32, 64));

      // defer-max rescale (T13)
      if (!__all(pm <= m)) {
        const float mn = fmaxf(m, pm);
        const float sc = exp2f(m - mn);
        m = mn; l *= sc;
        #pragma unroll
        for (int j = 0; j < 4; ++j)
          #pragma unroll
          for (int r = 0; r < 4; ++r) oacc[j][r] *= sc;
      }

      // P = 2^(S - m), row sum
      float p[4][4];
      #pragma unroll
      for (int n = 0; n < 4; ++n)
        #pragma unroll
        for (int r = 0; r < 4; ++r) p[n][r] = exp2f(sacc[n][r] - m);
      float rs = ((p[0][0] + p[0][1]) + (p[0][2] + p[0][3]))
               + ((p[1][0] + p[1][1]) + (p[1][2] + p[1][3]))
               + ((p[2][0] + p[2][1]) + (p[2][2] + p[2][3]))
               + ((p[3][0] + p[3][1]) + (p[3][2] + p[3][3]));
      rs += __shfl_xor(rs, 16, 64);
      rs += __shfl_xor(rs, 32, 64);
      l += rs;

      uint32_t w32[4][2];
      #pragma unroll
      for (int n = 0; n < 4; ++n)
        #pragma unroll
        for (int c = 0; c < 2; ++c)
          w32[n][c] = cvtpk(p[n][2 * c], p[n][2 * c + 1]);

      // O^T += V^T P^T  (V from LDS, swizzled reads)
      __builtin_amdgcn_s_setprio(1);
#if HAVE_MFMA161616
      short4v pb[4];
      #pragma unroll
      for (int n = 0; n < 4; ++n) {
        union { uint32_t u[2]; short4v s; } t;
        t.u[0] = w32[n][0]; t.u[1] = w32[n][1];
        pb[n] = t.s;
      }
      #pragma unroll
      for (int j = 0; j < 4; ++j) {
        const char* vr = vbt + (j * 16 + l16) * 128;
        #pragma unroll
        for (int n = 0; n < 4; ++n) {
          short4v vfn = *(const short4v*)(vr + ((n * 32 + lq * 8) ^ swz));
          oacc[j] = __builtin_amdgcn_mfma_f32_16x16x16bf16_1k(vfn, pb[n],
                                                              oacc[j], 0, 0, 0);
        }
      }
#else
      union { uint32_t u[4]; bf16x8 v; } pf0, pf1;
      #pragma unroll
      for (int aa = 0; aa < 4; ++aa) {
        const int src = l16 + ((((lq << 1) + (aa >> 1)) & 3) << 4);
        uint32_t lo0 = (uint32_t)__shfl((int)w32[0][aa & 1], src, 64);
        uint32_t hi0 = (uint32_t)__shfl((int)w32[1][aa & 1], src, 64);
        uint32_t lo1 = (uint32_t)__shfl((int)w32[2][aa & 1], src, 64);
        uint32_t hi1 = (uint32_t)__shfl((int)w32[3][aa & 1], src, 64);
        pf0.u[aa] = (lq & 2) ? hi0 : lo0;
        pf1.u[aa] = (lq & 2) ? hi1 : lo1;
      }
      #pragma unroll
      for (int j = 0; j < 4; ++j) {
        const char* vr = vbt + (j * 16 + l16) * 128;
        bf16x8 v0 = *(const bf16x8*)(vr + ((lq * 16) ^ swz));
        bf16x8 v1 = *(const bf16x8*)(vr + ((64 + lq * 16) ^ swz));
        oacc[j] = mfma16(v0, pf0.v, oacc[j]);
        oacc[j] = mfma16(v1, pf1.v, oacc[j]);
      }
#endif
      __builtin_amdgcn_s_setprio(0);

      __syncthreads();  // drains vmcnt (incl. staged prefetch) + closes reads
      cur ^= 1;
    }
  }

  // write unnormalized partials + (m,l); merge_kernel renormalizes
  float* obase = (quarter == 0)
      ? out : opart + (size_t)(quarter - 1) * (BATCH * SEQ * HDIM);
  const int qrow = q0 + wave * 16 + l16;
  #pragma unroll
  for (int j = 0; j < 4; ++j) {
    float4 o;
    o.x = oacc[j][0]; o.y = oacc[j][1]; o.z = oacc[j][2]; o.w = oacc[j][3];
    *(float4*)&obase[(bT + qrow) * HDIM + j * 16 + lq * 4] = o;
  }
  if (lq == 0) {
    float2 ml; ml.x = m; ml.y = l;
    mlw[quarter * (BATCH * SEQ) + bT + qrow] = ml;
  }
}

// ---------------------------------------------------------------------------
// Merge the four KV-quarter partials:
// out = sum_q w_q * O_q / sum_q w_q * l_q,  w_q = 2^(m_q - max_q m_q)
// ---------------------------------------------------------------------------
__global__ __launch_bounds__(256) void merge_kernel(
    float* __restrict__ out, const float* __restrict__ opart,
    const float2* __restrict__ mlw) {
  const int g   = blockIdx.x * 256 + threadIdx.x;  // 524288
  const int row = g >> 4;
  const int c4  = (g & 15) << 2;
  const float2 ml0 = mlw[row];
  const float2 ml1 = mlw[BATCH * SEQ + row];
  const float2 ml2 = mlw[2 * BATCH * SEQ + row];
  const float2 ml3 = mlw[3 * BATCH * SEQ + row];
  const float mm = fmaxf(fmaxf(ml0.x, ml1.x), fmaxf(ml2.x, ml3.x));
  const float w0 = exp2f(ml0.x - mm);
  const float w1 = exp2f(ml1.x - mm);
  const float w2 = exp2f(ml2.x - mm);
  const float w3 = exp2f(ml3.x - mm);
  const float inv =
      1.0f / (w0 * ml0.y + w1 * ml1.y + w2 * ml2.y + w3 * ml3.y);
  const size_t off = (size_t)row * HDIM + c4;
  const size_t stride = (size_t)BATCH * SEQ * HDIM;
  float4 a0 = *(const float4*)&out[off];
  float4 a1 = *(const float4*)&opart[off];
  float4 a2 = *(const float4*)&opart[off + stride];
  float4 a3 = *(const float4*)&opart[off + 2 * stride];
  float4 r;
  r.x = (w0 * a0.x + w1 * a1.x + w2 * a2.x + w3 * a3.x) * inv;
  r.y = (w0 * a0.y + w1 * a1.y + w2 * a2.y + w3 * a3.y) * inv;
  r.z = (w0 * a0.z + w1 * a1.z + w2 * a2.z + w3 * a3.z) * inv;
  r.w = (w0 * a0.w + w1 * a1.w + w2 * a2.w + w3 * a3.w) * inv;
  *(float4*)&out[off] = r;
}

// ---------------------------------------------------------------------------
extern "C" void kernel_launch(void* const* d_in, const int* in_sizes, int n_in,
                              void* d_out, int out_size, void* d_ws, size_t ws_size,
                              hipStream_t stream) {
  (void)in_sizes; (void)n_in; (void)out_size; (void)ws_size;
  const float* x  = (const float*)d_in[0];
  const float* Wq = (const float*)d_in[1];
  const float* Wk = (const float*)d_in[2];
  const float* Wv = (const float*)d_in[3];

  const size_t qkvb = (size_t)BATCH * SEQ * HDIM * sizeof(short);  // 4 MB each
  const size_t opb  = (size_t)BATCH * SEQ * HDIM * sizeof(float);  // 8 MB
  char* ws = (char*)d_ws;
  short*  qb    = (short*)(ws);
  short*  kb    = (short*)(ws + qkvb);
  short*  vT    = (short*)(ws + 2 * qkvb);
  float*  opart = (float*)(ws + 3 * qkvb);                          // 24 MB
  float2* mlw   = (float2*)(ws + 3 * qkvb + 3 * opb);               // 1 MB
  short*  Wt    = (short*)(ws + 3 * qkvb + 3 * opb +
                           (size_t)4 * BATCH * SEQ * sizeof(float2));

  wpack_kernel<<<dim3((192 * CDIM + 255) / 256), dim3(256), 0, stream>>>(Wq, Wk, Wv, Wt);
  qkv_kernel<<<dim3(BATCH * SEQ / 64), dim3(256), 0, stream>>>(x, Wt, qb, kb, vT);
  attn_kernel<<<dim3(2048), dim3(256), 0, stream>>>(qb, kb, vT, (float*)d_out, opart, mlw);
  merge_kernel<<<dim3(BATCH * SEQ * HDIM / 4 / 256), dim3(256), 0, stream>>>(
      (float*)d_out, opart, mlw);
}

// Round 8
// 74.185 us; speedup vs baseline: 3.3650x; 1.0777x over previous
//
#include <hip/hip_runtime.h>
#include <hip/hip_bf16.h>
#include <cstdint>
#include <cstddef>

#define BATCH 8
#define SEQ   4096
#define CDIM  384
#define HDIM  64

typedef __attribute__((ext_vector_type(8)))  __bf16 bf16x8;
typedef __attribute__((ext_vector_type(4)))  float  f32x4;
typedef __attribute__((ext_vector_type(16))) float  f32x16;
typedef __attribute__((ext_vector_type(4)))  short  short4v;

#if __has_builtin(__builtin_amdgcn_permlane32_swap)
#define HAVE_PERMLANE 1
#else
#define HAVE_PERMLANE 0
#endif

typedef __attribute__((address_space(3))) char lds_char;
typedef const __attribute__((address_space(1))) char gbl_char;

static __device__ __forceinline__ void gl_lds16(const void* g, void* l) {
  __builtin_amdgcn_global_load_lds((gbl_char*)g, (lds_char*)l, 16, 0, 0);
}

static __device__ __forceinline__ short f2bf(float f) {
  union { float f; uint32_t u; } v; v.f = f;
  uint32_t r = v.u + 0x7fffu + ((v.u >> 16) & 1u);
  return (short)(r >> 16);
}

static __device__ __forceinline__ uint32_t cvtpk(float lo, float hi) {
  uint32_t r;
  asm("v_cvt_pk_bf16_f32 %0, %1, %2" : "=v"(r) : "v"(lo), "v"(hi));
  return r;
}

static __device__ __forceinline__ f32x4 mfma16(bf16x8 a, bf16x8 b, f32x4 c) {
  return __builtin_amdgcn_mfma_f32_16x16x32_bf16(a, b, c, 0, 0, 0);
}

static __device__ __forceinline__ f32x16 mfma32(bf16x8 a, bf16x8 b, f32x16 c) {
  return __builtin_amdgcn_mfma_f32_32x32x16_bf16(a, b, c, 0, 0, 0);
}

static __device__ __forceinline__ f32x4 zero4() {
  f32x4 z = {0.f, 0.f, 0.f, 0.f};
  return z;
}

// exchange a float with the lane+-32 partner (VALU permlane; DS-shfl fallback)
static __device__ __forceinline__ float xhalf(float x, int hi) {
#if HAVE_PERMLANE
  union { float f; uint32_t u; } a; a.f = x;
  auto r = __builtin_amdgcn_permlane32_swap(a.u, a.u, false, false);
  union { uint32_t u; float f; } o; o.u = hi ? r[0] : r[1];
  return o.f;
#else
  return __shfl_xor(x, 32, 64);
#endif
}

// a' = {lanes<32: a ; lanes>=32: partner's b}, b' = {lanes<32: partner's a ; >=32: b}
static __device__ __forceinline__ void swap32(uint32_t& a, uint32_t& b, int hi) {
#if HAVE_PERMLANE
  auto r = __builtin_amdgcn_permlane32_swap(a, b, false, false);
  a = r[0]; b = r[1];
#else
  uint32_t sa = (uint32_t)__shfl_xor((int)a, 32, 64);
  uint32_t sb = (uint32_t)__shfl_xor((int)b, 32, 64);
  uint32_t na = hi ? sb : a;
  uint32_t nb = hi ? b : sa;
  a = na; b = nb;
#endif
}

// ---------------------------------------------------------------------------
// Pack Wq|Wk|Wv into Wt [192][384] bf16 (transposed, K contiguous).  Wq is
// prescaled by 0.125*log2(e): softmax runs in base 2 with no extra multiply.
// ---------------------------------------------------------------------------
__global__ __launch_bounds__(256) void wpack_kernel(
    const float* __restrict__ Wq, const float* __restrict__ Wk,
    const float* __restrict__ Wv, short* __restrict__ Wt) {
  int idx = blockIdx.x * 256 + threadIdx.x;
  if (idx >= 192 * CDIM) return;
  int n = idx / CDIM;
  int c = idx - n * CDIM;
  int m = n >> 6, h = n & 63;
  const float* W = (m == 0) ? Wq : (m == 1) ? Wk : Wv;
  float s = (m == 0) ? 0.18033688011112042f : 1.0f;  // 0.125 * log2(e)
  Wt[idx] = f2bf(W[c * HDIM + h] * s);
}

// ---------------------------------------------------------------------------
// QKV projection: x [32768][384] f32 -> q,k [b][t][64] bf16, v transposed
// vT [b][64][t] bf16.
// ---------------------------------------------------------------------------
#define XPAD 392

__global__ __launch_bounds__(256) void qkv_kernel(
    const float* __restrict__ x, const short* __restrict__ Wt,
    short* __restrict__ qb, short* __restrict__ kb, short* __restrict__ vT) {
  __shared__ short xs[64 * XPAD];
  const int tid = threadIdx.x;
  const int tokbase = blockIdx.x * 64;

  const float4* xg = (const float4*)(x + (size_t)tokbase * CDIM);
  for (int it = tid; it < 64 * (CDIM / 4); it += 256) {
    int r  = it / (CDIM / 4);
    int c4 = it - r * (CDIM / 4);
    float4 v = xg[it];
    uint2 st;
    st.x = cvtpk(v.x, v.y);
    st.y = cvtpk(v.z, v.w);
    *(uint2*)&xs[r * XPAD + c4 * 4] = st;
  }
  __syncthreads();

  const int wave = tid >> 6;
  const int lane = tid & 63;
  const int l16  = lane & 15;
  const int lq   = lane >> 4;

  f32x4 acc[4][3];
  #pragma unroll
  for (int ai = 0; ai < 4; ++ai)
    #pragma unroll
    for (int j = 0; j < 3; ++j) acc[ai][j] = zero4();

  #pragma unroll 2
  for (int kk = 0; kk < CDIM / 32; ++kk) {
    const int k0 = kk * 32;
    bf16x8 a[4];
    #pragma unroll
    for (int ai = 0; ai < 4; ++ai)
      a[ai] = *(const bf16x8*)&xs[(ai * 16 + l16) * XPAD + k0 + lq * 8];
    bf16x8 bb[3];
    #pragma unroll
    for (int j = 0; j < 3; ++j) {
      const int nt = wave * 3 + j;
      bb[j] = *(const bf16x8*)&Wt[(size_t)(nt * 16 + l16) * CDIM + k0 + lq * 8];
    }
    #pragma unroll
    for (int ai = 0; ai < 4; ++ai)
      #pragma unroll
      for (int j = 0; j < 3; ++j)
        acc[ai][j] = mfma16(a[ai], bb[j], acc[ai][j]);
  }

  const int b     = tokbase >> 12;
  const int tloc0 = tokbase & (SEQ - 1);
  #pragma unroll
  for (int j = 0; j < 3; ++j) {
    const int col = (wave * 3 + j) * 16 + l16;
    const int mat = col >> 6;
    const int h   = col & 63;
    #pragma unroll
    for (int ai = 0; ai < 4; ++ai) {
      const int row0 = ai * 16 + lq * 4;
      if (mat < 2) {
        short* dst = mat ? kb : qb;
        #pragma unroll
        for (int r = 0; r < 4; ++r)
          dst[(size_t)(tokbase + row0 + r) * HDIM + h] = f2bf(acc[ai][j][r]);
      } else {
        union { uint32_t u[2]; short4v s; } sv;
        sv.u[0] = cvtpk(acc[ai][j][0], acc[ai][j][1]);
        sv.u[1] = cvtpk(acc[ai][j][2], acc[ai][j][3]);
        *(short4v*)&vT[(size_t)(b * HDIM + h) * SEQ + (tloc0 + row0)] = sv.s;
      }
    }
  }
}

// ---------------------------------------------------------------------------
// Causal flash attention, 32x32 MFMA + 4-way KV split.
// 1024 blocks: b = bid&7, idx = bid>>3 in [0,128): qt = 31-(idx>>2) (128-row
// q-tile), quarter = idx&3 over nkv = 2qt+2 KV-tiles (LPT descending).
// 4 waves x 32 q-rows.  K/V staged to LDS (global_load_lds w16, dbuf,
// XOR-swizzled global source; identical to r5-r7 path).
// Swapped S^T = mfma32(K, Q): lane q = lane&31, s-rows = crow(reg,hi).
// Softmax fully in-register (permlane cross-half exchange, no DS shfl).
// P -> PV B-frags via 16 cvt_pk + 8 permlane32_swap (T12).
// Per-wave compute guard skips tiles entirely above the wave's rows.
// ---------------------------------------------------------------------------
__global__ __launch_bounds__(256, 3) void attn_kernel(
    const short* __restrict__ qb, const short* __restrict__ kb,
    const short* __restrict__ vT, float* __restrict__ out,
    float* __restrict__ opart, float2* __restrict__ mlw) {
  __shared__ short kvbuf[2][2][4096];  // [dbuf][K|V][64 rows x 128B], 32 KB

  const int tid  = threadIdx.x;
  const int wave = tid >> 6;
  const int lane = tid & 63;
  const int l31  = lane & 31;
  const int hi   = lane >> 5;
  const int bid  = blockIdx.x;
  const int b    = bid & 7;            // batch -> XCD pin (K/V L2-resident)
  const int idx  = bid >> 3;           // 0..127
  const int qt   = 31 - (idx >> 2);
  const int quarter = idx & 3;
  const int nkv  = 2 * qt + 2;
  const int base = nkv >> 2;
  const int rem  = nkv & 3;
  const int scnt = base + (quarter < rem ? 1 : 0);
  const int sbeg = quarter * base + (quarter < rem ? quarter : rem);
  const int q0   = qt << 7;
  const int qw0  = q0 + wave * 32;
  const size_t bT = (size_t)b * SEQ;

  const char* kg = (const char*)(kb + bT * HDIM);               // 128B rows
  const char* vg = (const char*)(vT + (size_t)b * HDIM * SEQ);  // 8192B rows

  // staging lane constants (dest linear; source col pre-swizzled so LDS
  // holds phys(r,c) = r*128 + (c ^ ((r&7)<<4)))
  const int rsub = lane >> 3;
  const int gcol = ((lane & 7) << 4) ^ (rsub << 4);
  const int krb  = wave * 16;

  f32x16 oacc[2];
  #pragma unroll
  for (int hb = 0; hb < 2; ++hb)
    #pragma unroll
    for (int r = 0; r < 16; ++r) oacc[hb][r] = 0.f;
  float m = -1e30f, l = 0.f;

  if (scnt > 0) {
    // Q fragments: Q[q=qw0+l31][k = 16t + hi*8 .. +7], t=0..3
    bf16x8 qf[4];
    {
      const short* qrow = qb + (bT + qw0 + l31) * HDIM + hi * 8;
      #pragma unroll
      for (int t = 0; t < 4; ++t)
        qf[t] = *(const bf16x8*)(qrow + 16 * t);
    }
    const int sw = (l31 & 7) << 4;
    int colk[4];  // byte col for k-step t (shared by K and V reads)
    #pragma unroll
    for (int t = 0; t < 4; ++t) colk[t] = ((t * 32) + hi * 16) ^ sw;
    const int rbase = l31 * 128;

    // prologue: stage tile sbeg
    {
      const int sf = sbeg << 6;
      #pragma unroll
      for (int i = 0; i < 2; ++i) {
        const int r = krb + i * 8;
        gl_lds16(kg + (size_t)(sf + r + rsub) * 128 + gcol,
                 (char*)&kvbuf[0][0][0] + r * 128);
        gl_lds16(vg + (size_t)(r + rsub) * 8192 + (size_t)sf * 2 + gcol,
                 (char*)&kvbuf[0][1][0] + r * 128);
      }
    }
    __syncthreads();

    int cur = 0;
    for (int it = 0; it < scnt; ++it) {
      const int s0 = (sbeg + it) << 6;
      if (it + 1 < scnt) {  // stage next tile into other buffer (async)
        const int s1 = s0 + 64;
        const int nb = cur ^ 1;
        #pragma unroll
        for (int i = 0; i < 2; ++i) {
          const int r = krb + i * 8;
          gl_lds16(kg + (size_t)(s1 + r + rsub) * 128 + gcol,
                   (char*)&kvbuf[nb][0][0] + r * 128);
          gl_lds16(vg + (size_t)(r + rsub) * 8192 + (size_t)s1 * 2 + gcol,
                   (char*)&kvbuf[nb][1][0] + r * 128);
        }
      }

      if (s0 <= qw0 + 31) {  // wave-uniform: skip tiles above this wave's rows
        const char* bufc = (const char*)kvbuf + cur * 16384;

        // ---- S^T = mfma32(K, Q): sacc[sb][reg] =
        //      S[q = qw0+l31][s = s0 + sb*32 + (reg&3)+8*(reg>>2)+4*hi] ----
        f32x16 sacc[2];
        #pragma unroll
        for (int sb = 0; sb < 2; ++sb) {
          #pragma unroll
          for (int r = 0; r < 16; ++r) sacc[sb][r] = 0.f;
          #pragma unroll
          for (int t = 0; t < 4; ++t) {
            bf16x8 kf = *(const bf16x8*)(bufc + sb * 4096 + rbase + colk[t]);
            sacc[sb] = mfma32(kf, qf[t], sacc[sb]);
          }
        }

        // ---- causal mask (diagonal tiles only; -3e38 so fully-masked lanes
        //      underflow to p=0 instead of 2^0) ----
        if (s0 + 63 > qw0) {
          const int qg = qw0 + l31;
          #pragma unroll
          for (int sb = 0; sb < 2; ++sb)
            #pragma unroll
            for (int r = 0; r < 16; ++r) {
              const int sg = s0 + sb * 32 + (r & 3) + 8 * (r >> 2) + 4 * hi;
              if (sg > qg) sacc[sb][r] = -3e38f;
            }
        }

        // ---- per-q max: 31 in-register + 1 cross-half exchange ----
        float pm = sacc[0][0];
        #pragma unroll
        for (int r = 1; r < 16; ++r) pm = fmaxf(pm, sacc[0][r]);
        #pragma unroll
        for (int r = 0; r < 16; ++r) pm = fmaxf(pm, sacc[1][r]);
        pm = fmaxf(pm, xhalf(pm, hi));

        // ---- defer-max rescale (T13, THR=8 in base-2) ----
        if (!__all(pm <= m + 8.f)) {
          const float mn = fmaxf(m, pm);
          const float sc = exp2f(m - mn);
          m = mn; l *= sc;
          #pragma unroll
          for (int hb = 0; hb < 2; ++hb)
            #pragma unroll
            for (int r = 0; r < 16; ++r) oacc[hb][r] *= sc;
        }

        // ---- P = 2^(S - m), row sum ----
        float p[2][16];
        float rs = 0.f;
        #pragma unroll
        for (int sb = 0; sb < 2; ++sb)
          #pragma unroll
          for (int r = 0; r < 16; ++r) {
            p[sb][r] = exp2f(sacc[sb][r] - m);
            rs += p[sb][r];
          }
        rs += xhalf(rs, hi);
        l += rs;

        // ---- pack to bf16 words: w[sb][g][c] covers s = sb*32+8g+4*hi+{2c,2c+1}
        uint32_t w[2][4][2];
        #pragma unroll
        for (int sb = 0; sb < 2; ++sb)
          #pragma unroll
          for (int g = 0; g < 4; ++g) {
            w[sb][g][0] = cvtpk(p[sb][4 * g + 0], p[sb][4 * g + 1]);
            w[sb][g][1] = cvtpk(p[sb][4 * g + 2], p[sb][4 * g + 3]);
          }

        // ---- assemble PV B-frags via permlane32_swap:
        // frag(sb,t) needs per lane (q,hi): k=s_local = 16t+8*hi+j;
        // j=0..3 from hi'=0 holder's w[2t+hi], j=4..7 from hi'=1's w[2t+hi].
        // swap32(a=w[2t][c], b=w[2t+1][c]) -> a' = hi' = 0 part, b' = hi'=1 part.
        bf16x8 pf[4];
        #pragma unroll
        for (int sb = 0; sb < 2; ++sb)
          #pragma unroll
          for (int t = 0; t < 2; ++t) {
            uint32_t a0 = w[sb][2 * t][0], b0 = w[sb][2 * t + 1][0];
            uint32_t a1 = w[sb][2 * t][1], b1 = w[sb][2 * t + 1][1];
            swap32(a0, b0, hi);
            swap32(a1, b1, hi);
            union { uint32_t u[4]; bf16x8 v; } uu;
            uu.u[0] = a0; uu.u[1] = a1; uu.u[2] = b0; uu.u[3] = b1;
            pf[sb * 2 + t] = uu.v;
          }

        // ---- O^T += V^T P^T (V from LDS, same col regs as K) ----
        __builtin_amdgcn_s_setprio(1);
        #pragma unroll
        for (int hb = 0; hb < 2; ++hb)
          #pragma unroll
          for (int ks = 0; ks < 4; ++ks) {
            bf16x8 vf = *(const bf16x8*)(bufc + 8192 + hb * 4096 + rbase + colk[ks]);
            oacc[hb] = mfma32(vf, pf[ks], oacc[hb]);
          }
        __builtin_amdgcn_s_setprio(0);
      }

      __syncthreads();  // drains vmcnt (staged prefetch) + closes LDS reads
      cur ^= 1;
    }
  }

  // ---- write unnormalized partials + (m,l); merge_kernel renormalizes ----
  float* obase = (quarter == 0)
      ? out : opart + (size_t)(quarter - 1) * (BATCH * SEQ * HDIM);
  const int q = qw0 + l31;
  #pragma unroll
  for (int hb = 0; hb < 2; ++hb)
    #pragma unroll
    for (int g = 0; g < 4; ++g) {
      float4 o;
      o.x = oacc[hb][4 * g + 0]; o.y = oacc[hb][4 * g + 1];
      o.z = oacc[hb][4 * g + 2]; o.w = oacc[hb][4 * g + 3];
      const int h0 = hb * 32 + 8 * g + 4 * hi;
      *(float4*)&obase[(bT + q) * HDIM + h0] = o;
    }
  if (lane < 32) {
    float2 ml; ml.x = m; ml.y = l;
    mlw[quarter * (BATCH * SEQ) + bT + q] = ml;
  }
}

// ---------------------------------------------------------------------------
// Merge the four KV-quarter partials:
// out = sum_q w_q * O_q / sum_q w_q * l_q,  w_q = 2^(m_q - max_q m_q)
// ---------------------------------------------------------------------------
__global__ __launch_bounds__(256) void merge_kernel(
    float* __restrict__ out, const float* __restrict__ opart,
    const float2* __restrict__ mlw) {
  const int g   = blockIdx.x * 256 + threadIdx.x;  // 524288
  const int row = g >> 4;
  const int c4  = (g & 15) << 2;
  const float2 ml0 = mlw[row];
  const float2 ml1 = mlw[BATCH * SEQ + row];
  const float2 ml2 = mlw[2 * BATCH * SEQ + row];
  const float2 ml3 = mlw[3 * BATCH * SEQ + row];
  const float mm = fmaxf(fmaxf(ml0.x, ml1.x), fmaxf(ml2.x, ml3.x));
  const float w0 = exp2f(ml0.x - mm);
  const float w1 = exp2f(ml1.x - mm);
  const float w2 = exp2f(ml2.x - mm);
  const float w3 = exp2f(ml3.x - mm);
  const float inv =
      1.0f / (w0 * ml0.y + w1 * ml1.y + w2 * ml2.y + w3 * ml3.y);
  const size_t off = (size_t)row * HDIM + c4;
  const size_t stride = (size_t)BATCH * SEQ * HDIM;
  float4 a0 = *(const float4*)&out[off];
  float4 a1 = *(const float4*)&opart[off];
  float4 a2 = *(const float4*)&opart[off + stride];
  float4 a3 = *(const float4*)&opart[off + 2 * stride];
  float4 r;
  r.x = (w0 * a0.x + w1 * a1.x + w2 * a2.x + w3 * a3.x) * inv;
  r.y = (w0 * a0.y + w1 * a1.y + w2 * a2.y + w3 * a3.y) * inv;
  r.z = (w0 * a0.z + w1 * a1.z + w2 * a2.z + w3 * a3.z) * inv;
  r.w = (w0 * a0.w + w1 * a1.w + w2 * a2.w + w3 * a3.w) * inv;
  *(float4*)&out[off] = r;
}

// ---------------------------------------------------------------------------
extern "C" void kernel_launch(void* const* d_in, const int* in_sizes, int n_in,
                              void* d_out, int out_size, void* d_ws, size_t ws_size,
                              hipStream_t stream) {
  (void)in_sizes; (void)n_in; (void)out_size; (void)ws_size;
  const float* x  = (const float*)d_in[0];
  const float* Wq = (const float*)d_in[1];
  const float* Wk = (const float*)d_in[2];
  const float* Wv = (const float*)d_in[3];

  const size_t qkvb = (size_t)BATCH * SEQ * HDIM * sizeof(short);  // 4 MB each
  const size_t opb  = (size_t)BATCH * SEQ * HDIM * sizeof(float);  // 8 MB
  char* ws = (char*)d_ws;
  short*  qb    = (short*)(ws);
  short*  kb    = (short*)(ws + qkvb);
  short*  vT    = (short*)(ws + 2 * qkvb);
  float*  opart = (float*)(ws + 3 * qkvb);                          // 24 MB
  float2* mlw   = (float2*)(ws + 3 * qkvb + 3 * opb);               // 1 MB
  short*  Wt    = (short*)(ws + 3 * qkvb + 3 * opb +
                           (size_t)4 * BATCH * SEQ * sizeof(float2));

  wpack_kernel<<<dim3((192 * CDIM + 255) / 256), dim3(256), 0, stream>>>(Wq, Wk, Wv, Wt);
  qkv_kernel<<<dim3(BATCH * SEQ / 64), dim3(256), 0, stream>>>(x, Wt, qb, kb, vT);
  attn_kernel<<<dim3(1024), dim3(256), 0, stream>>>(qb, kb, vT, (float*)d_out, opart, mlw);
  merge_kernel<<<dim3(BATCH * SEQ * HDIM / 4 / 256), dim3(256), 0, stream>>>(
      (float*)d_out, opart, mlw);
}